// Round 13
// baseline (59.930 us; speedup 1.0000x reference)
//
#include <hip/hip_runtime.h>
#include <stdint.h>
#include <math.h>

typedef uint32_t u32;
typedef uint64_t u64;

#define BB 8
#define CAT 10
#define HW 262144             // 512*512
#define WW 512
#define KSEL 500
#define CHUNKS 32             // prefilter WGs per plane
#define CH (HW / CHUNKS)      // 8192 elems per chunk
#define NCH (CAT * CHUNKS)    // 320 chunk-regions per batch
#define LCAP 64               // per-chunk candidate capacity (mean 3.3, >20 sigma)
#define CANDCAP 2048          // per-batch candidate capacity (mean 1049, sigma 32)
#define SLICES 16             // k_rank WGs per batch; SLICES*128 == CANDCAP
#define THRV 0.9996f
#define NB 4096               // fallback histogram buckets
#define NBQ 16                // NB / 256

// order-preserving float->u32 (ascending)
__device__ __forceinline__ u32 f2u(float f) {
    u32 b = __float_as_uint(f);
    return (b & 0x80000000u) ? ~b : (b | 0x80000000u);
}
__device__ __forceinline__ float u2f(u32 u) {
    u32 b = (u & 0x80000000u) ? (u ^ 0x80000000u) : ~u;
    return __uint_as_float(b);
}
__device__ __forceinline__ int bucketOf(float v) {   // exact monotone (pow2 scale)
    int b = (int)floorf(v * (float)NB);
    return min(max(b, 0), NB - 1);
}
// combined key: score desc, then (class asc, idx asc); combo < 10*2^18 <= 0x3FFFFF
__device__ __forceinline__ u64 make_key(float v, int c, int idx) {
    u32 combo = ((u32)c << 18) | (u32)idx;
    return ((u64)f2u(v) << 32) | (u32)(0x3FFFFFu - combo);
}

// ---------------- Kernel A: streaming prefilter (round-9 form, measured 12-15us) ----
__global__ __launch_bounds__(256) void k_prefilter(const float* __restrict__ heat,
                                                   u32* __restrict__ cnts,
                                                   u64* __restrict__ prebuf) {
    const int bc = blockIdx.y;       // 0..79
    const int chunk = blockIdx.x;    // 0..CHUNKS-1
    const int tid = threadIdx.x;
    const int c = bc % CAT;
    __shared__ u64 lbuf[LCAP];
    __shared__ u32 lcnt;
    if (tid == 0) lcnt = 0;
    __syncthreads();

    const float4* hp = (const float4*)(heat + (size_t)bc * HW + (size_t)chunk * CH);
    const int base_idx = chunk * CH;

    float4 r0 = hp[0 * 256 + tid];
    float4 r1 = hp[1 * 256 + tid];
    float4 r2 = hp[2 * 256 + tid];
    float4 r3 = hp[3 * 256 + tid];
    float4 r4 = hp[4 * 256 + tid];
    float4 r5 = hp[5 * 256 + tid];
    float4 r6 = hp[6 * 256 + tid];
    float4 r7 = hp[7 * 256 + tid];

    float m0 = fmaxf(fmaxf(r0.x, r0.y), fmaxf(r0.z, r0.w));
    float m1 = fmaxf(fmaxf(r1.x, r1.y), fmaxf(r1.z, r1.w));
    float m2 = fmaxf(fmaxf(r2.x, r2.y), fmaxf(r2.z, r2.w));
    float m3 = fmaxf(fmaxf(r3.x, r3.y), fmaxf(r3.z, r3.w));
    float m4 = fmaxf(fmaxf(r4.x, r4.y), fmaxf(r4.z, r4.w));
    float m5 = fmaxf(fmaxf(r5.x, r5.y), fmaxf(r5.z, r5.w));
    float m6 = fmaxf(fmaxf(r6.x, r6.y), fmaxf(r6.z, r6.w));
    float m7 = fmaxf(fmaxf(r7.x, r7.y), fmaxf(r7.z, r7.w));
    float m = fmaxf(fmaxf(fmaxf(m0, m1), fmaxf(m2, m3)),
                    fmaxf(fmaxf(m4, m5), fmaxf(m6, m7)));

    if (m > THRV) {                                  // ~1.3% of threads
        float4 rr[8] = {r0, r1, r2, r3, r4, r5, r6, r7};
#pragma unroll
        for (int k = 0; k < 8; ++k) {
            float vv[4] = {rr[k].x, rr[k].y, rr[k].z, rr[k].w};
            int e0 = base_idx + (k * 256 + tid) * 4;
#pragma unroll
            for (int j = 0; j < 4; ++j) {
                if (vv[j] > THRV) {
                    u32 pos = atomicAdd(&lcnt, 1u);
                    if (pos < LCAP) lbuf[pos] = make_key(vv[j], c, e0 + j);
                }
            }
        }
    }
    __syncthreads();
    u32 nmine = lcnt;
    u32 nw = nmine > LCAP ? LCAP : nmine;
    u64* pb = prebuf + ((size_t)bc * CHUNKS + chunk) * LCAP;
    if ((u32)tid < nw) pb[tid] = lbuf[tid];
    if (tid == 0) cnts[bc * CHUNKS + chunk] = nmine;  // raw; >LCAP signals overflow
}

// ---- fallback helpers (256 threads, never taken for this data) ----
__device__ __forceinline__ int find_b1_256(u32* h, u32* ps0, u32* ps1, int* b1_s) {
    const int tid = threadIdx.x;
    u32 p = 0;
#pragma unroll
    for (int q = 0; q < NBQ; ++q) p += h[tid * NBQ + q];
    ps0[tid] = p;
    __syncthreads();
    u32* src = ps0;
    u32* dst = ps1;
    for (int off = 1; off < 256; off <<= 1) {        // suffix scan
        u32 v = src[tid] + ((tid + off < 256) ? src[tid + off] : 0);
        dst[tid] = v;
        __syncthreads();
        u32* t = src; src = dst; dst = t;
    }
    u32 S_t = src[tid];
    u32 S_next = (tid < 255) ? src[tid + 1] : 0;
    if (S_t >= KSEL && (tid == 255 || S_next < KSEL)) {
        u32 run = (tid == 255) ? 0u : S_next;
        int b1 = tid * NBQ;
        for (int q = NBQ - 1; q >= 0; --q) {
            run += h[tid * NBQ + q];
            if (run >= KSEL) { b1 = tid * NBQ + q; break; }
        }
        *b1_s = b1;
    }
    __syncthreads();
    return *b1_s;
}

__device__ __forceinline__ void bitonic_sort_desc_256(u64* cand) {
    const int tid = threadIdx.x;
    for (int k2 = 2; k2 <= CANDCAP; k2 <<= 1) {
        for (int j = k2 >> 1; j > 0; j >>= 1) {
            for (int i = tid; i < CANDCAP; i += 256) {
                int ixj = i ^ j;
                if (ixj > i) {
                    u64 a = cand[i], b = cand[ixj];
                    bool up = ((i & k2) == 0);
                    if ((a < b) == up) { cand[i] = b; cand[ixj] = a; }
                }
            }
            __syncthreads();
        }
    }
}

// decode + write one winner (fallback path only; fast path writes inline)
__device__ __forceinline__ void decode_write(int b, int rank, float score, int cls, int ridx,
                                             const float* __restrict__ rot_sine,
                                             const float* __restrict__ rot_cosine,
                                             const float* __restrict__ hei,
                                             const float* __restrict__ dim,
                                             const float* __restrict__ vel,
                                             const float* __restrict__ reg,
                                             float* __restrict__ out) {
    float xs = (float)(ridx % WW);
    float ys = (float)(ridx / WW);
    size_t base = (size_t)b * HW;
    float r0 = reg[((size_t)(b * 2 + 0)) * HW + ridx];
    float r1 = reg[((size_t)(b * 2 + 1)) * HW + ridx];
    float rs = rot_sine[base + ridx];
    float rc = rot_cosine[base + ridx];
    float hg = hei[base + ridx];
    float d0 = dim[((size_t)(b * 3 + 0)) * HW + ridx];
    float d1 = dim[((size_t)(b * 3 + 1)) * HW + ridx];
    float d2 = dim[((size_t)(b * 3 + 2)) * HW + ridx];
    float v0 = vel[((size_t)(b * 2 + 0)) * HW + ridx];
    float v1 = vel[((size_t)(b * 2 + 1)) * HW + ridx];

    float x = (xs + r0) * 0.8f + (-51.2f);
    float y = (ys + r1) * 0.8f + (-51.2f);
    float rot = atan2f(rs, rc);

    size_t obase = ((size_t)b * KSEL + rank) * 9;
    out[obase + 0] = x;
    out[obase + 1] = y;
    out[obase + 2] = hg;
    out[obase + 3] = d0;
    out[obase + 4] = d1;
    out[obase + 5] = d2;
    out[obase + 6] = rot;
    out[obase + 7] = v0;
    out[obase + 8] = v1;

    const int NOUT = BB * KSEL;              // 4000
    out[9 * NOUT + b * KSEL + rank] = score;
    out[10 * NOUT + b * KSEL + rank] = (float)cls;
    bool keep = (x >= -61.2f) && (y >= -61.2f) && (hg >= -10.0f) &&
                (x <= 61.2f) && (y <= 61.2f) && (hg <= 10.0f) &&
                (score > 0.1f);
    out[11 * NOUT + b * KSEL + rank] = keep ? 1.0f : 0.0f;
}

// ---------------- Kernel B: rank-count top-k + decode (b128 reads, coalesced gather,
//                   prefetched decode operands); exact fallback inside ----
__global__ __launch_bounds__(256) void k_rank(const float* __restrict__ heat,
                                              const u32* __restrict__ cnts,
                                              const u64* __restrict__ prebuf,
                                              const float* __restrict__ rot_sine,
                                              const float* __restrict__ rot_cosine,
                                              const float* __restrict__ hei,
                                              const float* __restrict__ dim,
                                              const float* __restrict__ vel,
                                              const float* __restrict__ reg,
                                              float* __restrict__ out) {
    const int b = blockIdx.y;
    const int slice = blockIdx.x;
    const int tid = threadIdx.x;

    __shared__ __align__(16) char smem[77824];          // 76 KB, manually overlaid
    // fast path layout
    u64* keys    = (u64*)smem;                          // [2048] 16 KB
    u32* cc      = (u32*)(smem + 16384);                // [320]
    u32* sc0     = (u32*)(smem + 17920);                // [512]
    u32* sc1     = (u32*)(smem + 19968);                // [512]
    u32* partial = (u32*)(smem + 22016);                // [256]
    // fallback overlay (cc/sc/partial dead once fallback starts)
    u32* h    = (u32*)smem;                             // [4096] 16 KB
    u64* cand = (u64*)(smem + 16384);                   // [2048] 16 KB
    u32* ps0  = (u32*)(smem + 32768);                   // [256]
    u32* ps1  = (u32*)(smem + 33792);                   // [256]
    u64* s1k  = (u64*)(smem + 34816);                   // [5000] 40 KB -> ends 74816
    __shared__ int fb_s;
    __shared__ int b1_s;
    __shared__ int cnt_s;

    if (tid == 0) fb_s = 0;
    __syncthreads();
    const u32* cb = cnts + b * NCH;
    for (int i = tid; i < NCH; i += 256) {
        u32 v = cb[i];
        cc[i] = v;
        if (v > LCAP) fb_s = 1;                         // same-value race OK
    }
    __syncthreads();
    // exclusive prefix over cc via Hillis-Steele inclusive scan of shifted array (512 wide)
    sc0[tid]       = (tid >= 1 && tid - 1 < NCH) ? cc[tid - 1] : 0;
    sc0[tid + 256] = (tid + 255 < NCH) ? cc[tid + 255] : 0;
    __syncthreads();
    u32* src = sc0; u32* dst = sc1;
    for (int off = 1; off < 512; off <<= 1) {
        for (int i = tid; i < 512; i += 256)
            dst[i] = src[i] + ((i >= off) ? src[i - off] : 0);
        __syncthreads();
        u32* t = src; src = dst; dst = t;
    }
    u32 tot = src[NCH];
    if (tid == 0 && (tot < KSEL || tot > CANDCAP)) fb_s = 1;
    __syncthreads();
    int fb = fb_s;

    if (!fb) {
        // ---- gather: half-wave (32 lanes) per region, lane-parallel coalesced ----
        const int hw_id = tid >> 5;                     // 0..7
        const int l32 = tid & 31;
        for (int r2 = hw_id; r2 < NCH; r2 += 8) {       // 40 iters
            u32 n = cc[r2];
            u32 off = src[r2];                          // exclusive offset
            const u64* pb = prebuf + ((size_t)b * NCH + r2) * LCAP;
            if ((u32)l32 < n)      keys[off + l32]      = pb[l32];
            if ((u32)l32 + 32 < n) keys[off + l32 + 32] = pb[l32 + 32];
        }
        for (int i = tid; i < CANDCAP; i += 256)
            if ((u32)i >= tot) keys[i] = 0;             // pad: never outranks real keys
        __syncthreads();

        const int ci  = slice * 128 + (tid & 127);
        const int sub = tid >> 7;                       // wave-uniform (waves 0-1 vs 2-3)
        u64 mk = keys[ci];

        // prefetch decode operands (sub0 waves only); latency hides under rank loop.
        // For pad keys (ci>=tot) ridx=0x3FFFF -> in-bounds dummy loads, results unused.
        u32 combo = 0x3FFFFFu - (u32)(mk & 0xFFFFFFFFull);
        int cls = (int)(combo >> 18);
        int ridx = (int)(combo & 0x3FFFFu);
        float pr0 = 0, pr1 = 0, prs = 0, prc = 0, phg = 0;
        float pd0 = 0, pd1 = 0, pd2 = 0, pv0 = 0, pv1 = 0;
        if (sub == 0) {
            size_t base = (size_t)b * HW;
            pr0 = reg[((size_t)(b * 2 + 0)) * HW + ridx];
            pr1 = reg[((size_t)(b * 2 + 1)) * HW + ridx];
            prs = rot_sine[base + ridx];
            prc = rot_cosine[base + ridx];
            phg = hei[base + ridx];
            pd0 = dim[((size_t)(b * 3 + 0)) * HW + ridx];
            pd1 = dim[((size_t)(b * 3 + 1)) * HW + ridx];
            pd2 = dim[((size_t)(b * 3 + 2)) * HW + ridx];
            pv0 = vel[((size_t)(b * 2 + 0)) * HW + ridx];
            pv1 = vel[((size_t)(b * 2 + 1)) * HW + ridx];
        }

        // rank loop: b128 pair reads, tot-bounded, half-range per sub
        const ulonglong2* k2 = (const ulonglong2*)keys;
        u32 P  = (tot + 1) >> 1;                        // pairs holding real keys
        u32 Pm = (P + 1) >> 1;
        u32 p0 = sub ? Pm : 0, p1 = sub ? P : Pm;
        u32 r = 0;
#pragma unroll 8
        for (u32 p = p0; p < p1; ++p) {                 // broadcast ds_read_b128
            ulonglong2 kk = k2[p];
            r += (kk.x > mk) + (kk.y > mk);
        }
        partial[tid] = r;
        __syncthreads();
        if (tid < 128) {                                // these are sub0 threads
            int rank = (int)(partial[tid] + partial[tid + 128]);
            if (ci < (int)tot && rank < KSEL) {
                float score = u2f((u32)(mk >> 32));
                float xs = (float)(ridx & (WW - 1));
                float ys = (float)(ridx >> 9);
                float x = (xs + pr0) * 0.8f + (-51.2f);
                float y = (ys + pr1) * 0.8f + (-51.2f);
                float rot = atan2f(prs, prc);
                size_t obase = ((size_t)b * KSEL + rank) * 9;
                out[obase + 0] = x;
                out[obase + 1] = y;
                out[obase + 2] = phg;
                out[obase + 3] = pd0;
                out[obase + 4] = pd1;
                out[obase + 5] = pd2;
                out[obase + 6] = rot;
                out[obase + 7] = pv0;
                out[obase + 8] = pv1;
                const int NOUT = BB * KSEL;             // 4000
                out[9 * NOUT + b * KSEL + rank] = score;
                out[10 * NOUT + b * KSEL + rank] = (float)cls;
                bool keep = (x >= -61.2f) && (y >= -61.2f) && (phg >= -10.0f) &&
                            (x <= 61.2f) && (y <= 61.2f) && (phg <= 10.0f) &&
                            (score > 0.1f);
                out[11 * NOUT + b * KSEL + rank] = keep ? 1.0f : 0.0f;
            }
        }
        return;
    }

    // ---- exact fallback (not taken for this data; correctness safety net) ----
    if (slice != 0) return;
    for (int c = 0; c < CAT; ++c) {
        const float* hp = heat + (size_t)(b * CAT + c) * HW;
        for (int i = tid; i < NB; i += 256) h[i] = 0;
        if (tid == 0) cnt_s = 0;
        __syncthreads();
        for (int i = tid; i < HW; i += 256) atomicAdd(&h[bucketOf(hp[i])], 1u);
        __syncthreads();
        int b1 = find_b1_256(h, ps0, ps1, &b1_s);
        for (int i = tid; i < HW; i += 256) {
            float v = hp[i];
            if (bucketOf(v) >= b1) {
                int pos = atomicAdd(&cnt_s, 1);
                if (pos < CANDCAP)
                    cand[pos] = ((u64)f2u(v) << 32) | (u32)(~(u32)i);
            }
        }
        __syncthreads();
        int c2 = min(cnt_s, CANDCAP);
        for (int i = c2 + tid; i < CANDCAP; i += 256) cand[i] = 0;
        __syncthreads();
        bitonic_sort_desc_256(cand);
        for (int r2 = tid; r2 < KSEL; r2 += 256) s1k[c * KSEL + r2] = cand[r2];
        __syncthreads();
    }
    // stage 2 over s1k[5000], tie-break by flat position
    const int NCAND = CAT * KSEL;
    for (int i = tid; i < NB; i += 256) h[i] = 0;
    if (tid == 0) cnt_s = 0;
    __syncthreads();
    for (int i = tid; i < NCAND; i += 256)
        atomicAdd(&h[bucketOf(u2f((u32)(s1k[i] >> 32)))], 1u);
    __syncthreads();
    int b1 = find_b1_256(h, ps0, ps1, &b1_s);
    for (int i = tid; i < NCAND; i += 256) {
        u64 k1 = s1k[i];
        float v = u2f((u32)(k1 >> 32));
        if (bucketOf(v) >= b1) {
            int pos = atomicAdd(&cnt_s, 1);
            if (pos < CANDCAP)
                cand[pos] = (k1 & 0xFFFFFFFF00000000ull) | (u32)(~(u32)i);
        }
    }
    __syncthreads();
    int c2 = min(cnt_s, CANDCAP);
    for (int i = c2 + tid; i < CANDCAP; i += 256) cand[i] = 0;
    __syncthreads();
    bitonic_sort_desc_256(cand);
    for (int r2 = tid; r2 < KSEL; r2 += 256) {
        u64 kk = cand[r2];
        float score = u2f((u32)(kk >> 32));
        int flat = (int)(~(u32)kk);
        int cls = flat / KSEL;
        int ridx = (int)(~(u32)s1k[flat]);
        decode_write(b, r2, score, cls, ridx,
                     rot_sine, rot_cosine, hei, dim, vel, reg, out);
    }
}

extern "C" void kernel_launch(void* const* d_in, const int* in_sizes, int n_in,
                              void* d_out, int out_size, void* d_ws, size_t ws_size,
                              hipStream_t stream) {
    const float* heat       = (const float*)d_in[0];
    const float* rot_sine   = (const float*)d_in[1];
    const float* rot_cosine = (const float*)d_in[2];
    const float* hei        = (const float*)d_in[3];
    const float* dim        = (const float*)d_in[4];
    const float* vel        = (const float*)d_in[5];
    const float* reg        = (const float*)d_in[6];

    char* ws = (char*)d_ws;
    // layout: cnts 80*32*4 = 10240 B | pad to 16384 | prebuf 80*32*64*8 = 1310720 B
    u32* cnts   = (u32*)ws;
    u64* prebuf = (u64*)(ws + 16384);
    // no memset needed: every cnts slot is written unconditionally by k_prefilter

    k_prefilter<<<dim3(CHUNKS, BB * CAT), 256, 0, stream>>>(heat, cnts, prebuf);
    // DIAGNOSTIC: improved k_rank launched TWICE (idempotent — reads unchanged
    // cnts/prebuf, writes identical values). dur13 - dur14(next, single) = rank+node.
    k_rank<<<dim3(SLICES, BB), 256, 0, stream>>>(heat, cnts, prebuf,
                                                 rot_sine, rot_cosine, hei, dim, vel, reg,
                                                 (float*)d_out);
    k_rank<<<dim3(SLICES, BB), 256, 0, stream>>>(heat, cnts, prebuf,
                                                 rot_sine, rot_cosine, hei, dim, vel, reg,
                                                 (float*)d_out);
}

// Round 14
// 36.831 us; speedup vs baseline: 1.6271x; 1.6271x over previous
//
#include <hip/hip_runtime.h>
#include <stdint.h>
#include <math.h>

typedef uint32_t u32;
typedef uint64_t u64;

#define BB 8
#define CAT 10
#define HW 262144             // 512*512
#define WW 512
#define KSEL 500
#define CHUNKS 32             // prefilter WGs per plane
#define CH (HW / CHUNKS)      // 8192 elems per chunk
#define NCH (CAT * CHUNKS)    // 320 chunk-regions per batch
#define LCAP 64               // per-chunk candidate capacity (mean 3.3, >20 sigma)
#define CANDCAP 2048          // per-batch candidate capacity (mean 1049, sigma 32)
#define SLICES 16             // k_rank WGs per batch; SLICES*128 == CANDCAP
#define THRV 0.9996f
#define NB 4096               // fallback histogram buckets
#define NBQ 16                // NB / 256

// order-preserving float->u32 (ascending)
__device__ __forceinline__ u32 f2u(float f) {
    u32 b = __float_as_uint(f);
    return (b & 0x80000000u) ? ~b : (b | 0x80000000u);
}
__device__ __forceinline__ float u2f(u32 u) {
    u32 b = (u & 0x80000000u) ? (u ^ 0x80000000u) : ~u;
    return __uint_as_float(b);
}
__device__ __forceinline__ int bucketOf(float v) {   // exact monotone (pow2 scale)
    int b = (int)floorf(v * (float)NB);
    return min(max(b, 0), NB - 1);
}
// combined key: score desc, then (class asc, idx asc); combo < 10*2^18 <= 0x3FFFFF
__device__ __forceinline__ u64 make_key(float v, int c, int idx) {
    u32 combo = ((u32)c << 18) | (u32)idx;
    return ((u64)f2u(v) << 32) | (u32)(0x3FFFFFu - combo);
}

// ---------------- Kernel A: streaming prefilter (measured ~12us, unchanged) ----
__global__ __launch_bounds__(256) void k_prefilter(const float* __restrict__ heat,
                                                   u32* __restrict__ cnts,
                                                   u64* __restrict__ prebuf) {
    const int bc = blockIdx.y;       // 0..79
    const int chunk = blockIdx.x;    // 0..CHUNKS-1
    const int tid = threadIdx.x;
    const int c = bc % CAT;
    __shared__ u64 lbuf[LCAP];
    __shared__ u32 lcnt;
    if (tid == 0) lcnt = 0;
    __syncthreads();

    const float4* hp = (const float4*)(heat + (size_t)bc * HW + (size_t)chunk * CH);
    const int base_idx = chunk * CH;

    float4 r0 = hp[0 * 256 + tid];
    float4 r1 = hp[1 * 256 + tid];
    float4 r2 = hp[2 * 256 + tid];
    float4 r3 = hp[3 * 256 + tid];
    float4 r4 = hp[4 * 256 + tid];
    float4 r5 = hp[5 * 256 + tid];
    float4 r6 = hp[6 * 256 + tid];
    float4 r7 = hp[7 * 256 + tid];

    float m0 = fmaxf(fmaxf(r0.x, r0.y), fmaxf(r0.z, r0.w));
    float m1 = fmaxf(fmaxf(r1.x, r1.y), fmaxf(r1.z, r1.w));
    float m2 = fmaxf(fmaxf(r2.x, r2.y), fmaxf(r2.z, r2.w));
    float m3 = fmaxf(fmaxf(r3.x, r3.y), fmaxf(r3.z, r3.w));
    float m4 = fmaxf(fmaxf(r4.x, r4.y), fmaxf(r4.z, r4.w));
    float m5 = fmaxf(fmaxf(r5.x, r5.y), fmaxf(r5.z, r5.w));
    float m6 = fmaxf(fmaxf(r6.x, r6.y), fmaxf(r6.z, r6.w));
    float m7 = fmaxf(fmaxf(r7.x, r7.y), fmaxf(r7.z, r7.w));
    float m = fmaxf(fmaxf(fmaxf(m0, m1), fmaxf(m2, m3)),
                    fmaxf(fmaxf(m4, m5), fmaxf(m6, m7)));

    if (m > THRV) {                                  // ~1.3% of threads
        float4 rr[8] = {r0, r1, r2, r3, r4, r5, r6, r7};
#pragma unroll
        for (int k = 0; k < 8; ++k) {
            float vv[4] = {rr[k].x, rr[k].y, rr[k].z, rr[k].w};
            int e0 = base_idx + (k * 256 + tid) * 4;
#pragma unroll
            for (int j = 0; j < 4; ++j) {
                if (vv[j] > THRV) {
                    u32 pos = atomicAdd(&lcnt, 1u);
                    if (pos < LCAP) lbuf[pos] = make_key(vv[j], c, e0 + j);
                }
            }
        }
    }
    __syncthreads();
    u32 nmine = lcnt;
    u32 nw = nmine > LCAP ? LCAP : nmine;
    u64* pb = prebuf + ((size_t)bc * CHUNKS + chunk) * LCAP;
    if ((u32)tid < nw) pb[tid] = lbuf[tid];
    if (tid == 0) cnts[bc * CHUNKS + chunk] = nmine;  // raw; >LCAP signals overflow
}

// ---- fallback helpers (256 threads, never taken for this data) ----
__device__ __forceinline__ int find_b1_256(u32* h, u32* ps0, u32* ps1, int* b1_s) {
    const int tid = threadIdx.x;
    u32 p = 0;
#pragma unroll
    for (int q = 0; q < NBQ; ++q) p += h[tid * NBQ + q];
    ps0[tid] = p;
    __syncthreads();
    u32* src = ps0;
    u32* dst = ps1;
    for (int off = 1; off < 256; off <<= 1) {        // suffix scan
        u32 v = src[tid] + ((tid + off < 256) ? src[tid + off] : 0);
        dst[tid] = v;
        __syncthreads();
        u32* t = src; src = dst; dst = t;
    }
    u32 S_t = src[tid];
    u32 S_next = (tid < 255) ? src[tid + 1] : 0;
    if (S_t >= KSEL && (tid == 255 || S_next < KSEL)) {
        u32 run = (tid == 255) ? 0u : S_next;
        int b1 = tid * NBQ;
        for (int q = NBQ - 1; q >= 0; --q) {
            run += h[tid * NBQ + q];
            if (run >= KSEL) { b1 = tid * NBQ + q; break; }
        }
        *b1_s = b1;
    }
    __syncthreads();
    return *b1_s;
}

__device__ __forceinline__ void bitonic_sort_desc_256(u64* cand) {
    const int tid = threadIdx.x;
    for (int k2 = 2; k2 <= CANDCAP; k2 <<= 1) {
        for (int j = k2 >> 1; j > 0; j >>= 1) {
            for (int i = tid; i < CANDCAP; i += 256) {
                int ixj = i ^ j;
                if (ixj > i) {
                    u64 a = cand[i], b = cand[ixj];
                    bool up = ((i & k2) == 0);
                    if ((a < b) == up) { cand[i] = b; cand[ixj] = a; }
                }
            }
            __syncthreads();
        }
    }
}

// decode + write one winner (fallback path only; fast path writes inline)
__device__ __forceinline__ void decode_write(int b, int rank, float score, int cls, int ridx,
                                             const float* __restrict__ rot_sine,
                                             const float* __restrict__ rot_cosine,
                                             const float* __restrict__ hei,
                                             const float* __restrict__ dim,
                                             const float* __restrict__ vel,
                                             const float* __restrict__ reg,
                                             float* __restrict__ out) {
    float xs = (float)(ridx % WW);
    float ys = (float)(ridx / WW);
    size_t base = (size_t)b * HW;
    float r0 = reg[((size_t)(b * 2 + 0)) * HW + ridx];
    float r1 = reg[((size_t)(b * 2 + 1)) * HW + ridx];
    float rs = rot_sine[base + ridx];
    float rc = rot_cosine[base + ridx];
    float hg = hei[base + ridx];
    float d0 = dim[((size_t)(b * 3 + 0)) * HW + ridx];
    float d1 = dim[((size_t)(b * 3 + 1)) * HW + ridx];
    float d2 = dim[((size_t)(b * 3 + 2)) * HW + ridx];
    float v0 = vel[((size_t)(b * 2 + 0)) * HW + ridx];
    float v1 = vel[((size_t)(b * 2 + 1)) * HW + ridx];

    float x = (xs + r0) * 0.8f + (-51.2f);
    float y = (ys + r1) * 0.8f + (-51.2f);
    float rot = atan2f(rs, rc);

    size_t obase = ((size_t)b * KSEL + rank) * 9;
    out[obase + 0] = x;
    out[obase + 1] = y;
    out[obase + 2] = hg;
    out[obase + 3] = d0;
    out[obase + 4] = d1;
    out[obase + 5] = d2;
    out[obase + 6] = rot;
    out[obase + 7] = v0;
    out[obase + 8] = v1;

    const int NOUT = BB * KSEL;              // 4000
    out[9 * NOUT + b * KSEL + rank] = score;
    out[10 * NOUT + b * KSEL + rank] = (float)cls;
    bool keep = (x >= -61.2f) && (y >= -61.2f) && (hg >= -10.0f) &&
                (x <= 61.2f) && (y <= 61.2f) && (hg <= 10.0f) &&
                (score > 0.1f);
    out[11 * NOUT + b * KSEL + rank] = keep ? 1.0f : 0.0f;
}

// ---------------- Kernel B: rank-count top-k, minimal-barrier fast path ----
// scan: single-wave shuffle scan (0 barriers). gather: register-staged slab read
// (5 bounded waitcnt batches). rank/decode: round-13 verified logic.
__global__ __launch_bounds__(256) void k_rank(const float* __restrict__ heat,
                                              const u32* __restrict__ cnts,
                                              const u64* __restrict__ prebuf,
                                              const float* __restrict__ rot_sine,
                                              const float* __restrict__ rot_cosine,
                                              const float* __restrict__ hei,
                                              const float* __restrict__ dim,
                                              const float* __restrict__ vel,
                                              const float* __restrict__ reg,
                                              float* __restrict__ out) {
    const int b = blockIdx.y;
    const int slice = blockIdx.x;
    const int tid = threadIdx.x;

    __shared__ __align__(16) char smem[77824];          // 76 KB, manually overlaid
    // fast path layout
    u64* keys    = (u64*)smem;                          // [2048] 16 KB
    u32* cc      = (u32*)(smem + 16384);                // [320]
    u32* excl    = (u32*)(smem + 17664);                // [320]
    u32* partial = (u32*)(smem + 18944);                // [256]
    // fallback overlay (cc/excl/partial dead once fallback starts)
    u32* h    = (u32*)smem;                             // [4096] 16 KB
    u64* cand = (u64*)(smem + 16384);                   // [2048] 16 KB
    u32* ps0  = (u32*)(smem + 32768);                   // [256]
    u32* ps1  = (u32*)(smem + 33792);                   // [256]
    u64* s1k  = (u64*)(smem + 34816);                   // [5000] 40 KB -> ends 74816
    __shared__ int fb_s;
    __shared__ u32 tot_s;
    __shared__ int b1_s;
    __shared__ int cnt_s;

    // ---- single-wave scan of 320 counts: zero barriers inside ----
    if (tid < 64) {
        if (tid == 0) fb_s = 0;                        // wave-ordered before flag sets
        const u32* cb = cnts + b * NCH + tid * 5;
        u32 c0 = cb[0], c1 = cb[1], c2 = cb[2], c3 = cb[3], c4 = cb[4];
        if (c0 > LCAP || c1 > LCAP || c2 > LCAP || c3 > LCAP || c4 > LCAP) fb_s = 1;
        u32 l1 = c0 + c1, l2 = l1 + c2, l3 = l2 + c3, l4 = l3 + c4;
        u32 sum = l4;
#pragma unroll
        for (int off = 1; off < 64; off <<= 1) {       // wave-inclusive scan, no barriers
            u32 vv = __shfl_up(sum, off);
            if (tid >= off) sum += vv;
        }
        u32 base = sum - l4;                           // exclusive base for this lane
        int r = tid * 5;
        cc[r + 0] = c0; cc[r + 1] = c1; cc[r + 2] = c2; cc[r + 3] = c3; cc[r + 4] = c4;
        excl[r + 0] = base;
        excl[r + 1] = base + c0;
        excl[r + 2] = base + l1;
        excl[r + 3] = base + l2;
        excl[r + 4] = base + l3;
        if (tid == 63) {
            tot_s = sum;
            if (sum < KSEL || sum > CANDCAP) fb_s = 1;
        }
    }
    __syncthreads();                                   // barrier 1
    u32 tot = tot_s;
    int fb = fb_s;

    if (!fb) {
        // ---- gather: register-staged slab read (80 slots/thread, 5x16 batches) ----
        const u64* slab = prebuf + (size_t)b * NCH * LCAP;   // 20480 u64, contiguous
#pragma unroll 1
        for (int g = 0; g < 5; ++g) {
            u64 v[16];
#pragma unroll
            for (int k = 0; k < 16; ++k)               // 16 coalesced loads in flight
                v[k] = slab[(g * 16 + k) * 256 + tid];
#pragma unroll
            for (int k = 0; k < 16; ++k) {
                int s = (g * 16 + k) * 256 + tid;
                int r = s >> 6, l = s & 63;
                if ((u32)l < cc[r]) keys[excl[r] + l] = v[k];
            }
        }
        for (int i = tid; i < CANDCAP; i += 256)
            if ((u32)i >= tot) keys[i] = 0;            // pad: never outranks real keys
        __syncthreads();                               // barrier 2

        const int ci  = slice * 128 + (tid & 127);
        const int sub = tid >> 7;                      // wave-uniform (waves 0-1 vs 2-3)
        u64 mk = keys[ci];

        // prefetch decode operands (sub0 only); latency hides under rank loop.
        u32 combo = 0x3FFFFFu - (u32)(mk & 0xFFFFFFFFull);
        int cls = (int)(combo >> 18);
        int ridx = (int)(combo & 0x3FFFFu);
        float pr0 = 0, pr1 = 0, prs = 0, prc = 0, phg = 0;
        float pd0 = 0, pd1 = 0, pd2 = 0, pv0 = 0, pv1 = 0;
        if (sub == 0) {
            size_t base = (size_t)b * HW;
            pr0 = reg[((size_t)(b * 2 + 0)) * HW + ridx];
            pr1 = reg[((size_t)(b * 2 + 1)) * HW + ridx];
            prs = rot_sine[base + ridx];
            prc = rot_cosine[base + ridx];
            phg = hei[base + ridx];
            pd0 = dim[((size_t)(b * 3 + 0)) * HW + ridx];
            pd1 = dim[((size_t)(b * 3 + 1)) * HW + ridx];
            pd2 = dim[((size_t)(b * 3 + 2)) * HW + ridx];
            pv0 = vel[((size_t)(b * 2 + 0)) * HW + ridx];
            pv1 = vel[((size_t)(b * 2 + 1)) * HW + ridx];
        }

        // rank loop: b128 pair reads, tot-bounded, half-range per sub
        const ulonglong2* k2 = (const ulonglong2*)keys;
        u32 P  = (tot + 1) >> 1;
        u32 Pm = (P + 1) >> 1;
        u32 p0 = sub ? Pm : 0, p1 = sub ? P : Pm;
        u32 r = 0;
#pragma unroll 8
        for (u32 p = p0; p < p1; ++p) {                // broadcast ds_read_b128
            ulonglong2 kk = k2[p];
            r += (kk.x > mk) + (kk.y > mk);
        }
        partial[tid] = r;
        __syncthreads();                               // barrier 3
        if (tid < 128) {                               // sub0 threads hold prefetches
            int rank = (int)(partial[tid] + partial[tid + 128]);
            if (ci < (int)tot && rank < KSEL) {
                float score = u2f((u32)(mk >> 32));
                float xs = (float)(ridx & (WW - 1));
                float ys = (float)(ridx >> 9);
                float x = (xs + pr0) * 0.8f + (-51.2f);
                float y = (ys + pr1) * 0.8f + (-51.2f);
                float rot = atan2f(prs, prc);
                size_t obase = ((size_t)b * KSEL + rank) * 9;
                out[obase + 0] = x;
                out[obase + 1] = y;
                out[obase + 2] = phg;
                out[obase + 3] = pd0;
                out[obase + 4] = pd1;
                out[obase + 5] = pd2;
                out[obase + 6] = rot;
                out[obase + 7] = pv0;
                out[obase + 8] = pv1;
                const int NOUT = BB * KSEL;            // 4000
                out[9 * NOUT + b * KSEL + rank] = score;
                out[10 * NOUT + b * KSEL + rank] = (float)cls;
                bool keep = (x >= -61.2f) && (y >= -61.2f) && (phg >= -10.0f) &&
                            (x <= 61.2f) && (y <= 61.2f) && (phg <= 10.0f) &&
                            (score > 0.1f);
                out[11 * NOUT + b * KSEL + rank] = keep ? 1.0f : 0.0f;
            }
        }
        return;
    }

    // ---- exact fallback (not taken for this data; correctness safety net) ----
    if (slice != 0) return;
    for (int c = 0; c < CAT; ++c) {
        const float* hp = heat + (size_t)(b * CAT + c) * HW;
        for (int i = tid; i < NB; i += 256) h[i] = 0;
        if (tid == 0) cnt_s = 0;
        __syncthreads();
        for (int i = tid; i < HW; i += 256) atomicAdd(&h[bucketOf(hp[i])], 1u);
        __syncthreads();
        int b1 = find_b1_256(h, ps0, ps1, &b1_s);
        for (int i = tid; i < HW; i += 256) {
            float v = hp[i];
            if (bucketOf(v) >= b1) {
                int pos = atomicAdd(&cnt_s, 1);
                if (pos < CANDCAP)
                    cand[pos] = ((u64)f2u(v) << 32) | (u32)(~(u32)i);
            }
        }
        __syncthreads();
        int c2 = min(cnt_s, CANDCAP);
        for (int i = c2 + tid; i < CANDCAP; i += 256) cand[i] = 0;
        __syncthreads();
        bitonic_sort_desc_256(cand);
        for (int r2 = tid; r2 < KSEL; r2 += 256) s1k[c * KSEL + r2] = cand[r2];
        __syncthreads();
    }
    // stage 2 over s1k[5000], tie-break by flat position
    const int NCAND = CAT * KSEL;
    for (int i = tid; i < NB; i += 256) h[i] = 0;
    if (tid == 0) cnt_s = 0;
    __syncthreads();
    for (int i = tid; i < NCAND; i += 256)
        atomicAdd(&h[bucketOf(u2f((u32)(s1k[i] >> 32)))], 1u);
    __syncthreads();
    int b1 = find_b1_256(h, ps0, ps1, &b1_s);
    for (int i = tid; i < NCAND; i += 256) {
        u64 k1 = s1k[i];
        float v = u2f((u32)(k1 >> 32));
        if (bucketOf(v) >= b1) {
            int pos = atomicAdd(&cnt_s, 1);
            if (pos < CANDCAP)
                cand[pos] = (k1 & 0xFFFFFFFF00000000ull) | (u32)(~(u32)i);
        }
    }
    __syncthreads();
    int c2 = min(cnt_s, CANDCAP);
    for (int i = c2 + tid; i < CANDCAP; i += 256) cand[i] = 0;
    __syncthreads();
    bitonic_sort_desc_256(cand);
    for (int r2 = tid; r2 < KSEL; r2 += 256) {
        u64 kk = cand[r2];
        float score = u2f((u32)(kk >> 32));
        int flat = (int)(~(u32)kk);
        int cls = flat / KSEL;
        int ridx = (int)(~(u32)s1k[flat]);
        decode_write(b, r2, score, cls, ridx,
                     rot_sine, rot_cosine, hei, dim, vel, reg, out);
    }
}

extern "C" void kernel_launch(void* const* d_in, const int* in_sizes, int n_in,
                              void* d_out, int out_size, void* d_ws, size_t ws_size,
                              hipStream_t stream) {
    const float* heat       = (const float*)d_in[0];
    const float* rot_sine   = (const float*)d_in[1];
    const float* rot_cosine = (const float*)d_in[2];
    const float* hei        = (const float*)d_in[3];
    const float* dim        = (const float*)d_in[4];
    const float* vel        = (const float*)d_in[5];
    const float* reg        = (const float*)d_in[6];

    char* ws = (char*)d_ws;
    // layout: cnts 80*32*4 = 10240 B | pad to 16384 | prebuf 80*32*64*8 = 1310720 B
    u32* cnts   = (u32*)ws;
    u64* prebuf = (u64*)(ws + 16384);
    // no memset needed: every cnts slot is written unconditionally by k_prefilter

    k_prefilter<<<dim3(CHUNKS, BB * CAT), 256, 0, stream>>>(heat, cnts, prebuf);
    k_rank<<<dim3(SLICES, BB), 256, 0, stream>>>(heat, cnts, prebuf,
                                                 rot_sine, rot_cosine, hei, dim, vel, reg,
                                                 (float*)d_out);
}

// Round 15
// 30.245 us; speedup vs baseline: 1.9815x; 1.2178x over previous
//
#include <hip/hip_runtime.h>
#include <stdint.h>
#include <math.h>

typedef uint32_t u32;
typedef uint64_t u64;

#define BB 8
#define CAT 10
#define HW 262144             // 512*512
#define WW 512
#define KSEL 500
#define CHUNKS 32             // prefilter WGs per plane
#define CH (HW / CHUNKS)      // 8192 elems per chunk
#define NCH (CAT * CHUNKS)    // 320 chunk-regions per batch
#define LCAP 32               // per-chunk cap (mean 2.05, sigma 1.43 -> 21 sigma)
#define CANDCAP 1024          // per-batch cap (mean 655, sigma 26: >=500 @6s, <=1024 @14s)
#define SLICES 8              // k_rank WGs per batch; SLICES*128 == CANDCAP
#define THRV 0.99975f
#define NB 4096               // fallback histogram buckets
#define NBQ 16                // NB / 256
#define FBCAP 2048            // fallback sort capacity

// order-preserving float->u32 (ascending)
__device__ __forceinline__ u32 f2u(float f) {
    u32 b = __float_as_uint(f);
    return (b & 0x80000000u) ? ~b : (b | 0x80000000u);
}
__device__ __forceinline__ float u2f(u32 u) {
    u32 b = (u & 0x80000000u) ? (u ^ 0x80000000u) : ~u;
    return __uint_as_float(b);
}
__device__ __forceinline__ int bucketOf(float v) {   // exact monotone (pow2 scale)
    int b = (int)floorf(v * (float)NB);
    return min(max(b, 0), NB - 1);
}
// combined key: score desc, then (class asc, idx asc); combo < 10*2^18 <= 0x3FFFFF
__device__ __forceinline__ u64 make_key(float v, int c, int idx) {
    u32 combo = ((u32)c << 18) | (u32)idx;
    return ((u64)f2u(v) << 32) | (u32)(0x3FFFFFu - combo);
}

// ---------------- Kernel A: streaming prefilter (measured ~12us) ----
__global__ __launch_bounds__(256) void k_prefilter(const float* __restrict__ heat,
                                                   u32* __restrict__ cnts,
                                                   u64* __restrict__ prebuf) {
    const int bc = blockIdx.y;       // 0..79
    const int chunk = blockIdx.x;    // 0..CHUNKS-1
    const int tid = threadIdx.x;
    const int c = bc % CAT;
    __shared__ u64 lbuf[LCAP];
    __shared__ u32 lcnt;
    if (tid == 0) lcnt = 0;
    __syncthreads();

    const float4* hp = (const float4*)(heat + (size_t)bc * HW + (size_t)chunk * CH);
    const int base_idx = chunk * CH;

    float4 r0 = hp[0 * 256 + tid];
    float4 r1 = hp[1 * 256 + tid];
    float4 r2 = hp[2 * 256 + tid];
    float4 r3 = hp[3 * 256 + tid];
    float4 r4 = hp[4 * 256 + tid];
    float4 r5 = hp[5 * 256 + tid];
    float4 r6 = hp[6 * 256 + tid];
    float4 r7 = hp[7 * 256 + tid];

    float m0 = fmaxf(fmaxf(r0.x, r0.y), fmaxf(r0.z, r0.w));
    float m1 = fmaxf(fmaxf(r1.x, r1.y), fmaxf(r1.z, r1.w));
    float m2 = fmaxf(fmaxf(r2.x, r2.y), fmaxf(r2.z, r2.w));
    float m3 = fmaxf(fmaxf(r3.x, r3.y), fmaxf(r3.z, r3.w));
    float m4 = fmaxf(fmaxf(r4.x, r4.y), fmaxf(r4.z, r4.w));
    float m5 = fmaxf(fmaxf(r5.x, r5.y), fmaxf(r5.z, r5.w));
    float m6 = fmaxf(fmaxf(r6.x, r6.y), fmaxf(r6.z, r6.w));
    float m7 = fmaxf(fmaxf(r7.x, r7.y), fmaxf(r7.z, r7.w));
    float m = fmaxf(fmaxf(fmaxf(m0, m1), fmaxf(m2, m3)),
                    fmaxf(fmaxf(m4, m5), fmaxf(m6, m7)));

    if (m > THRV) {                                  // ~0.8% of threads
        float4 rr[8] = {r0, r1, r2, r3, r4, r5, r6, r7};
#pragma unroll
        for (int k = 0; k < 8; ++k) {
            float vv[4] = {rr[k].x, rr[k].y, rr[k].z, rr[k].w};
            int e0 = base_idx + (k * 256 + tid) * 4;
#pragma unroll
            for (int j = 0; j < 4; ++j) {
                if (vv[j] > THRV) {
                    u32 pos = atomicAdd(&lcnt, 1u);
                    if (pos < LCAP) lbuf[pos] = make_key(vv[j], c, e0 + j);
                }
            }
        }
    }
    __syncthreads();
    u32 nmine = lcnt;
    u32 nw = nmine > LCAP ? LCAP : nmine;
    u64* pb = prebuf + ((size_t)bc * CHUNKS + chunk) * LCAP;
    if ((u32)tid < nw) pb[tid] = lbuf[tid];
    if (tid == 0) cnts[bc * CHUNKS + chunk] = nmine;  // raw; >LCAP signals overflow
}

// ---- fallback helpers (256 threads, never taken for this data) ----
__device__ __forceinline__ int find_b1_256(u32* h, u32* ps0, u32* ps1, int* b1_s) {
    const int tid = threadIdx.x;
    u32 p = 0;
#pragma unroll
    for (int q = 0; q < NBQ; ++q) p += h[tid * NBQ + q];
    ps0[tid] = p;
    __syncthreads();
    u32* src = ps0;
    u32* dst = ps1;
    for (int off = 1; off < 256; off <<= 1) {        // suffix scan
        u32 v = src[tid] + ((tid + off < 256) ? src[tid + off] : 0);
        dst[tid] = v;
        __syncthreads();
        u32* t = src; src = dst; dst = t;
    }
    u32 S_t = src[tid];
    u32 S_next = (tid < 255) ? src[tid + 1] : 0;
    if (S_t >= KSEL && (tid == 255 || S_next < KSEL)) {
        u32 run = (tid == 255) ? 0u : S_next;
        int b1 = tid * NBQ;
        for (int q = NBQ - 1; q >= 0; --q) {
            run += h[tid * NBQ + q];
            if (run >= KSEL) { b1 = tid * NBQ + q; break; }
        }
        *b1_s = b1;
    }
    __syncthreads();
    return *b1_s;
}

__device__ __forceinline__ void bitonic_sort_desc_256(u64* cand) {   // sorts FBCAP keys
    const int tid = threadIdx.x;
    for (int k2 = 2; k2 <= FBCAP; k2 <<= 1) {
        for (int j = k2 >> 1; j > 0; j >>= 1) {
            for (int i = tid; i < FBCAP; i += 256) {
                int ixj = i ^ j;
                if (ixj > i) {
                    u64 a = cand[i], b = cand[ixj];
                    bool up = ((i & k2) == 0);
                    if ((a < b) == up) { cand[i] = b; cand[ixj] = a; }
                }
            }
            __syncthreads();
        }
    }
}

// decode + write one winner (fallback path only; fast path writes inline)
__device__ __forceinline__ void decode_write(int b, int rank, float score, int cls, int ridx,
                                             const float* __restrict__ rot_sine,
                                             const float* __restrict__ rot_cosine,
                                             const float* __restrict__ hei,
                                             const float* __restrict__ dim,
                                             const float* __restrict__ vel,
                                             const float* __restrict__ reg,
                                             float* __restrict__ out) {
    float xs = (float)(ridx % WW);
    float ys = (float)(ridx / WW);
    size_t base = (size_t)b * HW;
    float r0 = reg[((size_t)(b * 2 + 0)) * HW + ridx];
    float r1 = reg[((size_t)(b * 2 + 1)) * HW + ridx];
    float rs = rot_sine[base + ridx];
    float rc = rot_cosine[base + ridx];
    float hg = hei[base + ridx];
    float d0 = dim[((size_t)(b * 3 + 0)) * HW + ridx];
    float d1 = dim[((size_t)(b * 3 + 1)) * HW + ridx];
    float d2 = dim[((size_t)(b * 3 + 2)) * HW + ridx];
    float v0 = vel[((size_t)(b * 2 + 0)) * HW + ridx];
    float v1 = vel[((size_t)(b * 2 + 1)) * HW + ridx];

    float x = (xs + r0) * 0.8f + (-51.2f);
    float y = (ys + r1) * 0.8f + (-51.2f);
    float rot = atan2f(rs, rc);

    size_t obase = ((size_t)b * KSEL + rank) * 9;
    out[obase + 0] = x;
    out[obase + 1] = y;
    out[obase + 2] = hg;
    out[obase + 3] = d0;
    out[obase + 4] = d1;
    out[obase + 5] = d2;
    out[obase + 6] = rot;
    out[obase + 7] = v0;
    out[obase + 8] = v1;

    const int NOUT = BB * KSEL;              // 4000
    out[9 * NOUT + b * KSEL + rank] = score;
    out[10 * NOUT + b * KSEL + rank] = (float)cls;
    bool keep = (x >= -61.2f) && (y >= -61.2f) && (hg >= -10.0f) &&
                (x <= 61.2f) && (y <= 61.2f) && (hg <= 10.0f) &&
                (score > 0.1f);
    out[11 * NOUT + b * KSEL + rank] = keep ? 1.0f : 0.0f;
}

// ---------------- Kernel B: rank-count top-k, minimal exposed latency ----
__global__ __launch_bounds__(256) void k_rank(const float* __restrict__ heat,
                                              const u32* __restrict__ cnts,
                                              const u64* __restrict__ prebuf,
                                              const float* __restrict__ rot_sine,
                                              const float* __restrict__ rot_cosine,
                                              const float* __restrict__ hei,
                                              const float* __restrict__ dim,
                                              const float* __restrict__ vel,
                                              const float* __restrict__ reg,
                                              float* __restrict__ out) {
    const int b = blockIdx.y;
    const int slice = blockIdx.x;
    const int tid = threadIdx.x;

    __shared__ __align__(16) char smem[77824];          // 76 KB, manually overlaid
    // fast path layout
    u64* keys    = (u64*)smem;                          // [1024] 8 KB
    u32* cc      = (u32*)(smem + 8192);                 // [320]
    u32* excl    = (u32*)(smem + 9472);                 // [320]
    u32* partial = (u32*)(smem + 10752);                // [256] -> ends 11776
    // fallback overlay (fast-path arrays dead once fb decided)
    u32* h    = (u32*)smem;                             // [4096] 16 KB
    u64* cand = (u64*)(smem + 16384);                   // [2048] 16 KB
    u32* ps0  = (u32*)(smem + 32768);                   // [256]
    u32* ps1  = (u32*)(smem + 33792);                   // [256]
    u64* s1k  = (u64*)(smem + 34816);                   // [5000] 40 KB -> ends 74816
    __shared__ int fb_s;
    __shared__ u32 tot_s;
    __shared__ int b1_s;
    __shared__ int cnt_s;

    // ---- single-wave scan of 320 counts: zero barriers inside ----
    if (tid < 64) {
        if (tid == 0) fb_s = 0;                        // wave-ordered before flag sets
        const u32* cb = cnts + b * NCH + tid * 5;
        u32 c0 = cb[0], c1 = cb[1], c2 = cb[2], c3 = cb[3], c4 = cb[4];
        if (c0 > LCAP || c1 > LCAP || c2 > LCAP || c3 > LCAP || c4 > LCAP) fb_s = 1;
        u32 l1 = c0 + c1, l2 = l1 + c2, l3 = l2 + c3, l4 = l3 + c4;
        u32 sum = l4;
#pragma unroll
        for (int off = 1; off < 64; off <<= 1) {       // wave-inclusive scan, no barriers
            u32 vv = __shfl_up(sum, off);
            if (tid >= off) sum += vv;
        }
        u32 base = sum - l4;                           // exclusive base for this lane
        int r = tid * 5;
        cc[r + 0] = c0; cc[r + 1] = c1; cc[r + 2] = c2; cc[r + 3] = c3; cc[r + 4] = c4;
        excl[r + 0] = base;
        excl[r + 1] = base + c0;
        excl[r + 2] = base + l1;
        excl[r + 3] = base + l2;
        excl[r + 4] = base + l3;
        if (tid == 63) {
            tot_s = sum;
            if (sum < KSEL || sum > CANDCAP) fb_s = 1;
        }
    }
    __syncthreads();                                   // barrier 1
    u32 tot = tot_s;
    int fb = fb_s;

    if (!fb) {
        // ---- gather: register-staged slab read (40 slots/thread, 2x20 batches) ----
        const u64* slab = prebuf + (size_t)b * NCH * LCAP;   // 10240 u64, contiguous
#pragma unroll 1
        for (int g = 0; g < 2; ++g) {
            u64 v[20];
#pragma unroll
            for (int k = 0; k < 20; ++k)               // 20 coalesced loads in flight
                v[k] = slab[(g * 20 + k) * 256 + tid];
#pragma unroll
            for (int k = 0; k < 20; ++k) {
                int s = (g * 20 + k) * 256 + tid;
                int r = s >> 5, l = s & 31;            // LCAP=32 regions
                if ((u32)l < cc[r]) keys[excl[r] + l] = v[k];
            }
        }
        for (int i = tid; i < CANDCAP; i += 256)
            if ((u32)i >= tot) keys[i] = 0;            // pad: never outranks real keys
        __syncthreads();                               // barrier 2

        const int ci  = slice * 128 + (tid & 127);
        const int sub = tid >> 7;                      // wave-uniform (waves 0-1 vs 2-3)
        u64 mk = keys[ci];

        // prefetch decode operands (sub0 only); latency hides under rank loop.
        u32 combo = 0x3FFFFFu - (u32)(mk & 0xFFFFFFFFull);
        int cls = (int)(combo >> 18);
        int ridx = (int)(combo & 0x3FFFFu);
        float pr0 = 0, pr1 = 0, prs = 0, prc = 0, phg = 0;
        float pd0 = 0, pd1 = 0, pd2 = 0, pv0 = 0, pv1 = 0;
        if (sub == 0) {
            size_t base = (size_t)b * HW;
            pr0 = reg[((size_t)(b * 2 + 0)) * HW + ridx];
            pr1 = reg[((size_t)(b * 2 + 1)) * HW + ridx];
            prs = rot_sine[base + ridx];
            prc = rot_cosine[base + ridx];
            phg = hei[base + ridx];
            pd0 = dim[((size_t)(b * 3 + 0)) * HW + ridx];
            pd1 = dim[((size_t)(b * 3 + 1)) * HW + ridx];
            pd2 = dim[((size_t)(b * 3 + 2)) * HW + ridx];
            pv0 = vel[((size_t)(b * 2 + 0)) * HW + ridx];
            pv1 = vel[((size_t)(b * 2 + 1)) * HW + ridx];
        }

        // rank loop: b128 pair reads, tot-bounded, half-range per sub
        const ulonglong2* k2 = (const ulonglong2*)keys;
        u32 P  = (tot + 1) >> 1;                       // ~328 pairs
        u32 Pm = (P + 1) >> 1;
        u32 p0 = sub ? Pm : 0, p1 = sub ? P : Pm;
        u32 r = 0;
#pragma unroll 8
        for (u32 p = p0; p < p1; ++p) {                // broadcast ds_read_b128
            ulonglong2 kk = k2[p];
            r += (kk.x > mk) + (kk.y > mk);
        }
        partial[tid] = r;
        __syncthreads();                               // barrier 3
        if (tid < 128) {                               // sub0 threads hold prefetches
            int rank = (int)(partial[tid] + partial[tid + 128]);
            if (ci < (int)tot && rank < KSEL) {
                float score = u2f((u32)(mk >> 32));
                float xs = (float)(ridx & (WW - 1));
                float ys = (float)(ridx >> 9);
                float x = (xs + pr0) * 0.8f + (-51.2f);
                float y = (ys + pr1) * 0.8f + (-51.2f);
                float rot = atan2f(prs, prc);
                size_t obase = ((size_t)b * KSEL + rank) * 9;
                out[obase + 0] = x;
                out[obase + 1] = y;
                out[obase + 2] = phg;
                out[obase + 3] = pd0;
                out[obase + 4] = pd1;
                out[obase + 5] = pd2;
                out[obase + 6] = rot;
                out[obase + 7] = pv0;
                out[obase + 8] = pv1;
                const int NOUT = BB * KSEL;            // 4000
                out[9 * NOUT + b * KSEL + rank] = score;
                out[10 * NOUT + b * KSEL + rank] = (float)cls;
                bool keep = (x >= -61.2f) && (y >= -61.2f) && (phg >= -10.0f) &&
                            (x <= 61.2f) && (y <= 61.2f) && (phg <= 10.0f) &&
                            (score > 0.1f);
                out[11 * NOUT + b * KSEL + rank] = keep ? 1.0f : 0.0f;
            }
        }
        return;
    }

    // ---- exact fallback (not taken for this data; correctness safety net) ----
    if (slice != 0) return;
    for (int c = 0; c < CAT; ++c) {
        const float* hp = heat + (size_t)(b * CAT + c) * HW;
        for (int i = tid; i < NB; i += 256) h[i] = 0;
        if (tid == 0) cnt_s = 0;
        __syncthreads();
        for (int i = tid; i < HW; i += 256) atomicAdd(&h[bucketOf(hp[i])], 1u);
        __syncthreads();
        int b1 = find_b1_256(h, ps0, ps1, &b1_s);
        for (int i = tid; i < HW; i += 256) {
            float v = hp[i];
            if (bucketOf(v) >= b1) {
                int pos = atomicAdd(&cnt_s, 1);
                if (pos < FBCAP)
                    cand[pos] = ((u64)f2u(v) << 32) | (u32)(~(u32)i);
            }
        }
        __syncthreads();
        int c2 = min(cnt_s, FBCAP);
        for (int i = c2 + tid; i < FBCAP; i += 256) cand[i] = 0;
        __syncthreads();
        bitonic_sort_desc_256(cand);
        for (int r2 = tid; r2 < KSEL; r2 += 256) s1k[c * KSEL + r2] = cand[r2];
        __syncthreads();
    }
    // stage 2 over s1k[5000], tie-break by flat position
    const int NCAND = CAT * KSEL;
    for (int i = tid; i < NB; i += 256) h[i] = 0;
    if (tid == 0) cnt_s = 0;
    __syncthreads();
    for (int i = tid; i < NCAND; i += 256)
        atomicAdd(&h[bucketOf(u2f((u32)(s1k[i] >> 32)))], 1u);
    __syncthreads();
    int b1 = find_b1_256(h, ps0, ps1, &b1_s);
    for (int i = tid; i < NCAND; i += 256) {
        u64 k1 = s1k[i];
        float v = u2f((u32)(k1 >> 32));
        if (bucketOf(v) >= b1) {
            int pos = atomicAdd(&cnt_s, 1);
            if (pos < FBCAP)
                cand[pos] = (k1 & 0xFFFFFFFF00000000ull) | (u32)(~(u32)i);
        }
    }
    __syncthreads();
    int c2 = min(cnt_s, FBCAP);
    for (int i = c2 + tid; i < FBCAP; i += 256) cand[i] = 0;
    __syncthreads();
    bitonic_sort_desc_256(cand);
    for (int r2 = tid; r2 < KSEL; r2 += 256) {
        u64 kk = cand[r2];
        float score = u2f((u32)(kk >> 32));
        int flat = (int)(~(u32)kk);
        int cls = flat / KSEL;
        int ridx = (int)(~(u32)s1k[flat]);
        decode_write(b, r2, score, cls, ridx,
                     rot_sine, rot_cosine, hei, dim, vel, reg, out);
    }
}

extern "C" void kernel_launch(void* const* d_in, const int* in_sizes, int n_in,
                              void* d_out, int out_size, void* d_ws, size_t ws_size,
                              hipStream_t stream) {
    const float* heat       = (const float*)d_in[0];
    const float* rot_sine   = (const float*)d_in[1];
    const float* rot_cosine = (const float*)d_in[2];
    const float* hei        = (const float*)d_in[3];
    const float* dim        = (const float*)d_in[4];
    const float* vel        = (const float*)d_in[5];
    const float* reg        = (const float*)d_in[6];

    char* ws = (char*)d_ws;
    // layout: cnts 80*32*4 = 10240 B | pad to 16384 | prebuf 80*32*32*8 = 655360 B
    u32* cnts   = (u32*)ws;
    u64* prebuf = (u64*)(ws + 16384);
    // no memset needed: every cnts slot is written unconditionally by k_prefilter

    k_prefilter<<<dim3(CHUNKS, BB * CAT), 256, 0, stream>>>(heat, cnts, prebuf);
    k_rank<<<dim3(SLICES, BB), 256, 0, stream>>>(heat, cnts, prebuf,
                                                 rot_sine, rot_cosine, hei, dim, vel, reg,
                                                 (float*)d_out);
}

// Round 16
// 27.847 us; speedup vs baseline: 2.1521x; 1.0861x over previous
//
#include <hip/hip_runtime.h>
#include <stdint.h>
#include <math.h>

typedef uint32_t u32;
typedef uint64_t u64;

#define BB 8
#define CAT 10
#define HW 262144             // 512*512
#define WW 512
#define KSEL 500
#define CHUNKS 32             // prefilter WGs per plane
#define CH (HW / CHUNKS)      // 8192 elems per chunk
#define NCH (CAT * CHUNKS)    // 320 chunk-regions per batch
#define LCAP 16               // per-chunk cap (Poisson mean 2.05 -> P(>16) ~ 1e-12)
#define CANDCAP 1024          // per-batch cap (mean 655, sigma 26: >=500 @6s, <=1024 @14s)
#define SLICES 8              // k_rank WGs per batch; SLICES*128 == CANDCAP
#define THRV 0.99975f
#define NB 4096               // fallback histogram buckets
#define NBQ 16                // NB / 256
#define FBCAP 2048            // fallback sort capacity

// order-preserving float->u32 (ascending)
__device__ __forceinline__ u32 f2u(float f) {
    u32 b = __float_as_uint(f);
    return (b & 0x80000000u) ? ~b : (b | 0x80000000u);
}
__device__ __forceinline__ float u2f(u32 u) {
    u32 b = (u & 0x80000000u) ? (u ^ 0x80000000u) : ~u;
    return __uint_as_float(b);
}
__device__ __forceinline__ int bucketOf(float v) {   // exact monotone (pow2 scale)
    int b = (int)floorf(v * (float)NB);
    return min(max(b, 0), NB - 1);
}
// combined key: score desc, then (class asc, idx asc); combo < 10*2^18 <= 0x3FFFFF
__device__ __forceinline__ u64 make_key(float v, int c, int idx) {
    u32 combo = ((u32)c << 18) | (u32)idx;
    return ((u64)f2u(v) << 32) | (u32)(0x3FFFFFu - combo);
}

// ---------------- Kernel A: streaming prefilter (measured ~12us = 7 TB/s) ----
__global__ __launch_bounds__(256) void k_prefilter(const float* __restrict__ heat,
                                                   u32* __restrict__ cnts,
                                                   u64* __restrict__ prebuf) {
    const int bc = blockIdx.y;       // 0..79
    const int chunk = blockIdx.x;    // 0..CHUNKS-1
    const int tid = threadIdx.x;
    const int c = bc % CAT;
    __shared__ u64 lbuf[LCAP];
    __shared__ u32 lcnt;
    if (tid == 0) lcnt = 0;
    __syncthreads();

    const float4* hp = (const float4*)(heat + (size_t)bc * HW + (size_t)chunk * CH);
    const int base_idx = chunk * CH;

    float4 r0 = hp[0 * 256 + tid];
    float4 r1 = hp[1 * 256 + tid];
    float4 r2 = hp[2 * 256 + tid];
    float4 r3 = hp[3 * 256 + tid];
    float4 r4 = hp[4 * 256 + tid];
    float4 r5 = hp[5 * 256 + tid];
    float4 r6 = hp[6 * 256 + tid];
    float4 r7 = hp[7 * 256 + tid];

    float m0 = fmaxf(fmaxf(r0.x, r0.y), fmaxf(r0.z, r0.w));
    float m1 = fmaxf(fmaxf(r1.x, r1.y), fmaxf(r1.z, r1.w));
    float m2 = fmaxf(fmaxf(r2.x, r2.y), fmaxf(r2.z, r2.w));
    float m3 = fmaxf(fmaxf(r3.x, r3.y), fmaxf(r3.z, r3.w));
    float m4 = fmaxf(fmaxf(r4.x, r4.y), fmaxf(r4.z, r4.w));
    float m5 = fmaxf(fmaxf(r5.x, r5.y), fmaxf(r5.z, r5.w));
    float m6 = fmaxf(fmaxf(r6.x, r6.y), fmaxf(r6.z, r6.w));
    float m7 = fmaxf(fmaxf(r7.x, r7.y), fmaxf(r7.z, r7.w));
    float m = fmaxf(fmaxf(fmaxf(m0, m1), fmaxf(m2, m3)),
                    fmaxf(fmaxf(m4, m5), fmaxf(m6, m7)));

    if (m > THRV) {                                  // ~0.8% of threads
        float4 rr[8] = {r0, r1, r2, r3, r4, r5, r6, r7};
#pragma unroll
        for (int k = 0; k < 8; ++k) {
            float vv[4] = {rr[k].x, rr[k].y, rr[k].z, rr[k].w};
            int e0 = base_idx + (k * 256 + tid) * 4;
#pragma unroll
            for (int j = 0; j < 4; ++j) {
                if (vv[j] > THRV) {
                    u32 pos = atomicAdd(&lcnt, 1u);
                    if (pos < LCAP) lbuf[pos] = make_key(vv[j], c, e0 + j);
                }
            }
        }
    }
    __syncthreads();
    u32 nmine = lcnt;
    u32 nw = nmine > LCAP ? LCAP : nmine;
    u64* pb = prebuf + ((size_t)bc * CHUNKS + chunk) * LCAP;
    if ((u32)tid < nw) pb[tid] = lbuf[tid];
    if (tid == 0) cnts[bc * CHUNKS + chunk] = nmine;  // raw; >LCAP signals overflow
}

// ---- fallback helpers (256 threads, never taken for this data) ----
__device__ __forceinline__ int find_b1_256(u32* h, u32* ps0, u32* ps1, int* b1_s) {
    const int tid = threadIdx.x;
    u32 p = 0;
#pragma unroll
    for (int q = 0; q < NBQ; ++q) p += h[tid * NBQ + q];
    ps0[tid] = p;
    __syncthreads();
    u32* src = ps0;
    u32* dst = ps1;
    for (int off = 1; off < 256; off <<= 1) {        // suffix scan
        u32 v = src[tid] + ((tid + off < 256) ? src[tid + off] : 0);
        dst[tid] = v;
        __syncthreads();
        u32* t = src; src = dst; dst = t;
    }
    u32 S_t = src[tid];
    u32 S_next = (tid < 255) ? src[tid + 1] : 0;
    if (S_t >= KSEL && (tid == 255 || S_next < KSEL)) {
        u32 run = (tid == 255) ? 0u : S_next;
        int b1 = tid * NBQ;
        for (int q = NBQ - 1; q >= 0; --q) {
            run += h[tid * NBQ + q];
            if (run >= KSEL) { b1 = tid * NBQ + q; break; }
        }
        *b1_s = b1;
    }
    __syncthreads();
    return *b1_s;
}

__device__ __forceinline__ void bitonic_sort_desc_256(u64* cand) {   // sorts FBCAP keys
    const int tid = threadIdx.x;
    for (int k2 = 2; k2 <= FBCAP; k2 <<= 1) {
        for (int j = k2 >> 1; j > 0; j >>= 1) {
            for (int i = tid; i < FBCAP; i += 256) {
                int ixj = i ^ j;
                if (ixj > i) {
                    u64 a = cand[i], b = cand[ixj];
                    bool up = ((i & k2) == 0);
                    if ((a < b) == up) { cand[i] = b; cand[ixj] = a; }
                }
            }
            __syncthreads();
        }
    }
}

// decode + write one winner (fallback path only; fast path writes inline)
__device__ __forceinline__ void decode_write(int b, int rank, float score, int cls, int ridx,
                                             const float* __restrict__ rot_sine,
                                             const float* __restrict__ rot_cosine,
                                             const float* __restrict__ hei,
                                             const float* __restrict__ dim,
                                             const float* __restrict__ vel,
                                             const float* __restrict__ reg,
                                             float* __restrict__ out) {
    float xs = (float)(ridx % WW);
    float ys = (float)(ridx / WW);
    size_t base = (size_t)b * HW;
    float r0 = reg[((size_t)(b * 2 + 0)) * HW + ridx];
    float r1 = reg[((size_t)(b * 2 + 1)) * HW + ridx];
    float rs = rot_sine[base + ridx];
    float rc = rot_cosine[base + ridx];
    float hg = hei[base + ridx];
    float d0 = dim[((size_t)(b * 3 + 0)) * HW + ridx];
    float d1 = dim[((size_t)(b * 3 + 1)) * HW + ridx];
    float d2 = dim[((size_t)(b * 3 + 2)) * HW + ridx];
    float v0 = vel[((size_t)(b * 2 + 0)) * HW + ridx];
    float v1 = vel[((size_t)(b * 2 + 1)) * HW + ridx];

    float x = (xs + r0) * 0.8f + (-51.2f);
    float y = (ys + r1) * 0.8f + (-51.2f);
    float rot = atan2f(rs, rc);

    size_t obase = ((size_t)b * KSEL + rank) * 9;
    out[obase + 0] = x;
    out[obase + 1] = y;
    out[obase + 2] = hg;
    out[obase + 3] = d0;
    out[obase + 4] = d1;
    out[obase + 5] = d2;
    out[obase + 6] = rot;
    out[obase + 7] = v0;
    out[obase + 8] = v1;

    const int NOUT = BB * KSEL;              // 4000
    out[9 * NOUT + b * KSEL + rank] = score;
    out[10 * NOUT + b * KSEL + rank] = (float)cls;
    bool keep = (x >= -61.2f) && (y >= -61.2f) && (hg >= -10.0f) &&
                (x <= 61.2f) && (y <= 61.2f) && (hg <= 10.0f) &&
                (score > 0.1f);
    out[11 * NOUT + b * KSEL + rank] = keep ? 1.0f : 0.0f;
}

// ---------------- Kernel B: rank-count top-k, single exposed gather round ----
__global__ __launch_bounds__(256) void k_rank(const float* __restrict__ heat,
                                              const u32* __restrict__ cnts,
                                              const u64* __restrict__ prebuf,
                                              const float* __restrict__ rot_sine,
                                              const float* __restrict__ rot_cosine,
                                              const float* __restrict__ hei,
                                              const float* __restrict__ dim,
                                              const float* __restrict__ vel,
                                              const float* __restrict__ reg,
                                              float* __restrict__ out) {
    const int b = blockIdx.y;
    const int slice = blockIdx.x;
    const int tid = threadIdx.x;

    __shared__ __align__(16) char smem[77824];          // 76 KB, manually overlaid
    // fast path layout
    u64* keys    = (u64*)smem;                          // [1024] 8 KB
    u32* cc      = (u32*)(smem + 8192);                 // [320]
    u32* excl    = (u32*)(smem + 9472);                 // [320]
    u32* partial = (u32*)(smem + 10752);                // [256] -> ends 11776
    // fallback overlay (fast-path arrays dead once fb decided)
    u32* h    = (u32*)smem;                             // [4096] 16 KB
    u64* cand = (u64*)(smem + 16384);                   // [2048] 16 KB
    u32* ps0  = (u32*)(smem + 32768);                   // [256]
    u32* ps1  = (u32*)(smem + 33792);                   // [256]
    u64* s1k  = (u64*)(smem + 34816);                   // [5000] 40 KB -> ends 74816
    __shared__ int fb_s;
    __shared__ u32 tot_s;
    __shared__ int b1_s;
    __shared__ int cnt_s;

    // ---- single-wave scan of 320 counts: zero barriers inside ----
    if (tid < 64) {
        if (tid == 0) fb_s = 0;                        // wave-ordered before flag sets
        const u32* cb = cnts + b * NCH + tid * 5;
        u32 c0 = cb[0], c1 = cb[1], c2 = cb[2], c3 = cb[3], c4 = cb[4];
        if (c0 > LCAP || c1 > LCAP || c2 > LCAP || c3 > LCAP || c4 > LCAP) fb_s = 1;
        u32 l1 = c0 + c1, l2 = l1 + c2, l3 = l2 + c3, l4 = l3 + c4;
        u32 sum = l4;
#pragma unroll
        for (int off = 1; off < 64; off <<= 1) {       // wave-inclusive scan, no barriers
            u32 vv = __shfl_up(sum, off);
            if (tid >= off) sum += vv;
        }
        u32 base = sum - l4;                           // exclusive base for this lane
        int r = tid * 5;
        cc[r + 0] = c0; cc[r + 1] = c1; cc[r + 2] = c2; cc[r + 3] = c3; cc[r + 4] = c4;
        excl[r + 0] = base;
        excl[r + 1] = base + c0;
        excl[r + 2] = base + l1;
        excl[r + 3] = base + l2;
        excl[r + 4] = base + l3;
        if (tid == 63) {
            tot_s = sum;
            if (sum < KSEL || sum > CANDCAP) fb_s = 1;
        }
    }
    __syncthreads();                                   // barrier 1
    u32 tot = tot_s;
    int fb = fb_s;

    if (!fb) {
        // ---- gather: ONE register-staged slab read (20 slots/thread) ----
        const u64* slab = prebuf + (size_t)b * NCH * LCAP;   // 5120 u64, contiguous
        u64 v[20];
#pragma unroll
        for (int k = 0; k < 20; ++k)                   // 20 coalesced loads in flight
            v[k] = slab[k * 256 + tid];
#pragma unroll
        for (int k = 0; k < 20; ++k) {
            int s = k * 256 + tid;
            int r = s >> 4, l = s & 15;                // LCAP=16 regions
            if ((u32)l < cc[r]) keys[excl[r] + l] = v[k];
        }
        for (int i = tid; i < CANDCAP; i += 256)
            if ((u32)i >= tot) keys[i] = 0;            // pad: never outranks real keys
        __syncthreads();                               // barrier 2

        const int ci  = slice * 128 + (tid & 127);
        const int sub = tid >> 7;                      // wave-uniform (waves 0-1 vs 2-3)
        u64 mk = keys[ci];

        // prefetch decode operands (sub0 only); latency hides under rank loop.
        u32 combo = 0x3FFFFFu - (u32)(mk & 0xFFFFFFFFull);
        int cls = (int)(combo >> 18);
        int ridx = (int)(combo & 0x3FFFFu);
        float pr0 = 0, pr1 = 0, prs = 0, prc = 0, phg = 0;
        float pd0 = 0, pd1 = 0, pd2 = 0, pv0 = 0, pv1 = 0;
        if (sub == 0) {
            size_t base = (size_t)b * HW;
            pr0 = reg[((size_t)(b * 2 + 0)) * HW + ridx];
            pr1 = reg[((size_t)(b * 2 + 1)) * HW + ridx];
            prs = rot_sine[base + ridx];
            prc = rot_cosine[base + ridx];
            phg = hei[base + ridx];
            pd0 = dim[((size_t)(b * 3 + 0)) * HW + ridx];
            pd1 = dim[((size_t)(b * 3 + 1)) * HW + ridx];
            pd2 = dim[((size_t)(b * 3 + 2)) * HW + ridx];
            pv0 = vel[((size_t)(b * 2 + 0)) * HW + ridx];
            pv1 = vel[((size_t)(b * 2 + 1)) * HW + ridx];
        }

        // rank loop: b128 pair reads, tot-bounded, half-range per sub
        const ulonglong2* k2 = (const ulonglong2*)keys;
        u32 P  = (tot + 1) >> 1;                       // ~328 pairs
        u32 Pm = (P + 1) >> 1;
        u32 p0 = sub ? Pm : 0, p1 = sub ? P : Pm;
        u32 r = 0;
#pragma unroll 8
        for (u32 p = p0; p < p1; ++p) {                // broadcast ds_read_b128
            ulonglong2 kk = k2[p];
            r += (kk.x > mk) + (kk.y > mk);
        }
        partial[tid] = r;
        __syncthreads();                               // barrier 3
        if (tid < 128) {                               // sub0 threads hold prefetches
            int rank = (int)(partial[tid] + partial[tid + 128]);
            if (ci < (int)tot && rank < KSEL) {
                float score = u2f((u32)(mk >> 32));
                float xs = (float)(ridx & (WW - 1));
                float ys = (float)(ridx >> 9);
                float x = (xs + pr0) * 0.8f + (-51.2f);
                float y = (ys + pr1) * 0.8f + (-51.2f);
                float rot = atan2f(prs, prc);
                size_t obase = ((size_t)b * KSEL + rank) * 9;
                out[obase + 0] = x;
                out[obase + 1] = y;
                out[obase + 2] = phg;
                out[obase + 3] = pd0;
                out[obase + 4] = pd1;
                out[obase + 5] = pd2;
                out[obase + 6] = rot;
                out[obase + 7] = pv0;
                out[obase + 8] = pv1;
                const int NOUT = BB * KSEL;            // 4000
                out[9 * NOUT + b * KSEL + rank] = score;
                out[10 * NOUT + b * KSEL + rank] = (float)cls;
                bool keep = (x >= -61.2f) && (y >= -61.2f) && (phg >= -10.0f) &&
                            (x <= 61.2f) && (y <= 61.2f) && (phg <= 10.0f) &&
                            (score > 0.1f);
                out[11 * NOUT + b * KSEL + rank] = keep ? 1.0f : 0.0f;
            }
        }
        return;
    }

    // ---- exact fallback (not taken for this data; correctness safety net) ----
    if (slice != 0) return;
    for (int c = 0; c < CAT; ++c) {
        const float* hp = heat + (size_t)(b * CAT + c) * HW;
        for (int i = tid; i < NB; i += 256) h[i] = 0;
        if (tid == 0) cnt_s = 0;
        __syncthreads();
        for (int i = tid; i < HW; i += 256) atomicAdd(&h[bucketOf(hp[i])], 1u);
        __syncthreads();
        int b1 = find_b1_256(h, ps0, ps1, &b1_s);
        for (int i = tid; i < HW; i += 256) {
            float v = hp[i];
            if (bucketOf(v) >= b1) {
                int pos = atomicAdd(&cnt_s, 1);
                if (pos < FBCAP)
                    cand[pos] = ((u64)f2u(v) << 32) | (u32)(~(u32)i);
            }
        }
        __syncthreads();
        int c2 = min(cnt_s, FBCAP);
        for (int i = c2 + tid; i < FBCAP; i += 256) cand[i] = 0;
        __syncthreads();
        bitonic_sort_desc_256(cand);
        for (int r2 = tid; r2 < KSEL; r2 += 256) s1k[c * KSEL + r2] = cand[r2];
        __syncthreads();
    }
    // stage 2 over s1k[5000], tie-break by flat position
    const int NCAND = CAT * KSEL;
    for (int i = tid; i < NB; i += 256) h[i] = 0;
    if (tid == 0) cnt_s = 0;
    __syncthreads();
    for (int i = tid; i < NCAND; i += 256)
        atomicAdd(&h[bucketOf(u2f((u32)(s1k[i] >> 32)))], 1u);
    __syncthreads();
    int b1 = find_b1_256(h, ps0, ps1, &b1_s);
    for (int i = tid; i < NCAND; i += 256) {
        u64 k1 = s1k[i];
        float v = u2f((u32)(k1 >> 32));
        if (bucketOf(v) >= b1) {
            int pos = atomicAdd(&cnt_s, 1);
            if (pos < FBCAP)
                cand[pos] = (k1 & 0xFFFFFFFF00000000ull) | (u32)(~(u32)i);
        }
    }
    __syncthreads();
    int c2 = min(cnt_s, FBCAP);
    for (int i = c2 + tid; i < FBCAP; i += 256) cand[i] = 0;
    __syncthreads();
    bitonic_sort_desc_256(cand);
    for (int r2 = tid; r2 < KSEL; r2 += 256) {
        u64 kk = cand[r2];
        float score = u2f((u32)(kk >> 32));
        int flat = (int)(~(u32)kk);
        int cls = flat / KSEL;
        int ridx = (int)(~(u32)s1k[flat]);
        decode_write(b, r2, score, cls, ridx,
                     rot_sine, rot_cosine, hei, dim, vel, reg, out);
    }
}

extern "C" void kernel_launch(void* const* d_in, const int* in_sizes, int n_in,
                              void* d_out, int out_size, void* d_ws, size_t ws_size,
                              hipStream_t stream) {
    const float* heat       = (const float*)d_in[0];
    const float* rot_sine   = (const float*)d_in[1];
    const float* rot_cosine = (const float*)d_in[2];
    const float* hei        = (const float*)d_in[3];
    const float* dim        = (const float*)d_in[4];
    const float* vel        = (const float*)d_in[5];
    const float* reg        = (const float*)d_in[6];

    char* ws = (char*)d_ws;
    // layout: cnts 80*32*4 = 10240 B | pad to 16384 | prebuf 80*32*16*8 = 327680 B
    u32* cnts   = (u32*)ws;
    u64* prebuf = (u64*)(ws + 16384);
    // no memset needed: every cnts slot is written unconditionally by k_prefilter

    k_prefilter<<<dim3(CHUNKS, BB * CAT), 256, 0, stream>>>(heat, cnts, prebuf);
    k_rank<<<dim3(SLICES, BB), 256, 0, stream>>>(heat, cnts, prebuf,
                                                 rot_sine, rot_cosine, hei, dim, vel, reg,
                                                 (float*)d_out);
}

// Round 17
// 27.667 us; speedup vs baseline: 2.1661x; 1.0065x over previous
//
#include <hip/hip_runtime.h>
#include <stdint.h>
#include <math.h>

typedef uint32_t u32;
typedef uint64_t u64;

#define BB 8
#define CAT 10
#define HW 262144             // 512*512
#define WW 512
#define KSEL 500
#define CHUNKS 32             // prefilter WGs per plane
#define CH (HW / CHUNKS)      // 8192 elems per chunk
#define NCH (CAT * CHUNKS)    // 320 chunk-regions per batch
#define LCAP 16               // per-chunk cap (Poisson mean 2.05 -> P(>16) ~ 1e-12)
#define CANDCAP 1024          // per-batch cap (mean 655, sigma 26: >=500 @6s, <=1024 @14s)
#define SLICES 8              // k_rank WGs per batch; SLICES*128 == CANDCAP
#define THRV 0.99975f
#define NB 4096               // fallback histogram buckets
#define NBQ 16                // NB / 256
#define FBCAP 2048            // fallback sort capacity

// order-preserving float->u32 (ascending)
__device__ __forceinline__ u32 f2u(float f) {
    u32 b = __float_as_uint(f);
    return (b & 0x80000000u) ? ~b : (b | 0x80000000u);
}
__device__ __forceinline__ float u2f(u32 u) {
    u32 b = (u & 0x80000000u) ? (u ^ 0x80000000u) : ~u;
    return __uint_as_float(b);
}
__device__ __forceinline__ int bucketOf(float v) {   // exact monotone (pow2 scale)
    int b = (int)floorf(v * (float)NB);
    return min(max(b, 0), NB - 1);
}
// combined key: score desc, then (class asc, idx asc); combo < 10*2^18 <= 0x3FFFFF
__device__ __forceinline__ u64 make_key(float v, int c, int idx) {
    u32 combo = ((u32)c << 18) | (u32)idx;
    return ((u64)f2u(v) << 32) | (u32)(0x3FFFFFu - combo);
}

// ---------------- Kernel A: streaming prefilter (measured ~12us = 7 TB/s) ----
__global__ __launch_bounds__(256) void k_prefilter(const float* __restrict__ heat,
                                                   u32* __restrict__ cnts,
                                                   u64* __restrict__ prebuf) {
    const int bc = blockIdx.y;       // 0..79
    const int chunk = blockIdx.x;    // 0..CHUNKS-1
    const int tid = threadIdx.x;
    const int c = bc % CAT;
    __shared__ u64 lbuf[LCAP];
    __shared__ u32 lcnt;
    if (tid == 0) lcnt = 0;
    __syncthreads();

    const float4* hp = (const float4*)(heat + (size_t)bc * HW + (size_t)chunk * CH);
    const int base_idx = chunk * CH;

    float4 r0 = hp[0 * 256 + tid];
    float4 r1 = hp[1 * 256 + tid];
    float4 r2 = hp[2 * 256 + tid];
    float4 r3 = hp[3 * 256 + tid];
    float4 r4 = hp[4 * 256 + tid];
    float4 r5 = hp[5 * 256 + tid];
    float4 r6 = hp[6 * 256 + tid];
    float4 r7 = hp[7 * 256 + tid];

    float m0 = fmaxf(fmaxf(r0.x, r0.y), fmaxf(r0.z, r0.w));
    float m1 = fmaxf(fmaxf(r1.x, r1.y), fmaxf(r1.z, r1.w));
    float m2 = fmaxf(fmaxf(r2.x, r2.y), fmaxf(r2.z, r2.w));
    float m3 = fmaxf(fmaxf(r3.x, r3.y), fmaxf(r3.z, r3.w));
    float m4 = fmaxf(fmaxf(r4.x, r4.y), fmaxf(r4.z, r4.w));
    float m5 = fmaxf(fmaxf(r5.x, r5.y), fmaxf(r5.z, r5.w));
    float m6 = fmaxf(fmaxf(r6.x, r6.y), fmaxf(r6.z, r6.w));
    float m7 = fmaxf(fmaxf(r7.x, r7.y), fmaxf(r7.z, r7.w));
    float m = fmaxf(fmaxf(fmaxf(m0, m1), fmaxf(m2, m3)),
                    fmaxf(fmaxf(m4, m5), fmaxf(m6, m7)));

    if (m > THRV) {                                  // ~0.8% of threads
        float4 rr[8] = {r0, r1, r2, r3, r4, r5, r6, r7};
#pragma unroll
        for (int k = 0; k < 8; ++k) {
            float vv[4] = {rr[k].x, rr[k].y, rr[k].z, rr[k].w};
            int e0 = base_idx + (k * 256 + tid) * 4;
#pragma unroll
            for (int j = 0; j < 4; ++j) {
                if (vv[j] > THRV) {
                    u32 pos = atomicAdd(&lcnt, 1u);
                    if (pos < LCAP) lbuf[pos] = make_key(vv[j], c, e0 + j);
                }
            }
        }
    }
    __syncthreads();
    u32 nmine = lcnt;
    u32 nw = nmine > LCAP ? LCAP : nmine;
    u64* pb = prebuf + ((size_t)bc * CHUNKS + chunk) * LCAP;
    if ((u32)tid < nw) pb[tid] = lbuf[tid];
    if (tid == 0) cnts[bc * CHUNKS + chunk] = nmine;  // raw; >LCAP signals overflow
}

// ---- fallback helpers (256 threads, never taken for this data) ----
__device__ __forceinline__ int find_b1_256(u32* h, u32* ps0, u32* ps1, int* b1_s) {
    const int tid = threadIdx.x;
    u32 p = 0;
#pragma unroll
    for (int q = 0; q < NBQ; ++q) p += h[tid * NBQ + q];
    ps0[tid] = p;
    __syncthreads();
    u32* src = ps0;
    u32* dst = ps1;
    for (int off = 1; off < 256; off <<= 1) {        // suffix scan
        u32 v = src[tid] + ((tid + off < 256) ? src[tid + off] : 0);
        dst[tid] = v;
        __syncthreads();
        u32* t = src; src = dst; dst = t;
    }
    u32 S_t = src[tid];
    u32 S_next = (tid < 255) ? src[tid + 1] : 0;
    if (S_t >= KSEL && (tid == 255 || S_next < KSEL)) {
        u32 run = (tid == 255) ? 0u : S_next;
        int b1 = tid * NBQ;
        for (int q = NBQ - 1; q >= 0; --q) {
            run += h[tid * NBQ + q];
            if (run >= KSEL) { b1 = tid * NBQ + q; break; }
        }
        *b1_s = b1;
    }
    __syncthreads();
    return *b1_s;
}

__device__ __forceinline__ void bitonic_sort_desc_256(u64* cand) {   // sorts FBCAP keys
    const int tid = threadIdx.x;
    for (int k2 = 2; k2 <= FBCAP; k2 <<= 1) {
        for (int j = k2 >> 1; j > 0; j >>= 1) {
            for (int i = tid; i < FBCAP; i += 256) {
                int ixj = i ^ j;
                if (ixj > i) {
                    u64 a = cand[i], b = cand[ixj];
                    bool up = ((i & k2) == 0);
                    if ((a < b) == up) { cand[i] = b; cand[ixj] = a; }
                }
            }
            __syncthreads();
        }
    }
}

// decode + write one winner (fallback path only; fast path writes inline)
__device__ __forceinline__ void decode_write(int b, int rank, float score, int cls, int ridx,
                                             const float* __restrict__ rot_sine,
                                             const float* __restrict__ rot_cosine,
                                             const float* __restrict__ hei,
                                             const float* __restrict__ dim,
                                             const float* __restrict__ vel,
                                             const float* __restrict__ reg,
                                             float* __restrict__ out) {
    float xs = (float)(ridx % WW);
    float ys = (float)(ridx / WW);
    size_t base = (size_t)b * HW;
    float r0 = reg[((size_t)(b * 2 + 0)) * HW + ridx];
    float r1 = reg[((size_t)(b * 2 + 1)) * HW + ridx];
    float rs = rot_sine[base + ridx];
    float rc = rot_cosine[base + ridx];
    float hg = hei[base + ridx];
    float d0 = dim[((size_t)(b * 3 + 0)) * HW + ridx];
    float d1 = dim[((size_t)(b * 3 + 1)) * HW + ridx];
    float d2 = dim[((size_t)(b * 3 + 2)) * HW + ridx];
    float v0 = vel[((size_t)(b * 2 + 0)) * HW + ridx];
    float v1 = vel[((size_t)(b * 2 + 1)) * HW + ridx];

    float x = (xs + r0) * 0.8f + (-51.2f);
    float y = (ys + r1) * 0.8f + (-51.2f);
    float rot = atan2f(rs, rc);

    size_t obase = ((size_t)b * KSEL + rank) * 9;
    out[obase + 0] = x;
    out[obase + 1] = y;
    out[obase + 2] = hg;
    out[obase + 3] = d0;
    out[obase + 4] = d1;
    out[obase + 5] = d2;
    out[obase + 6] = rot;
    out[obase + 7] = v0;
    out[obase + 8] = v1;

    const int NOUT = BB * KSEL;              // 4000
    out[9 * NOUT + b * KSEL + rank] = score;
    out[10 * NOUT + b * KSEL + rank] = (float)cls;
    bool keep = (x >= -61.2f) && (y >= -61.2f) && (hg >= -10.0f) &&
                (x <= 61.2f) && (y <= 61.2f) && (hg <= 10.0f) &&
                (score > 0.1f);
    out[11 * NOUT + b * KSEL + rank] = keep ? 1.0f : 0.0f;
}

// ---------------- Kernel B: rank-count top-k; slab loads issued at entry so the
//                   cnts round + scan overlap with them (T14 issue-early) ----
__global__ __launch_bounds__(256) void k_rank(const float* __restrict__ heat,
                                              const u32* __restrict__ cnts,
                                              const u64* __restrict__ prebuf,
                                              const float* __restrict__ rot_sine,
                                              const float* __restrict__ rot_cosine,
                                              const float* __restrict__ hei,
                                              const float* __restrict__ dim,
                                              const float* __restrict__ vel,
                                              const float* __restrict__ reg,
                                              float* __restrict__ out) {
    const int b = blockIdx.y;
    const int slice = blockIdx.x;
    const int tid = threadIdx.x;

    __shared__ __align__(16) char smem[77824];          // 76 KB, manually overlaid
    // fast path layout
    u64* keys    = (u64*)smem;                          // [1024] 8 KB
    u32* cc      = (u32*)(smem + 8192);                 // [320]
    u32* excl    = (u32*)(smem + 9472);                 // [320]
    u32* partial = (u32*)(smem + 10752);                // [256] -> ends 11776
    // fallback overlay (fast-path arrays dead once fb decided)
    u32* h    = (u32*)smem;                             // [4096] 16 KB
    u64* cand = (u64*)(smem + 16384);                   // [2048] 16 KB
    u32* ps0  = (u32*)(smem + 32768);                   // [256]
    u32* ps1  = (u32*)(smem + 33792);                   // [256]
    u64* s1k  = (u64*)(smem + 34816);                   // [5000] 40 KB -> ends 74816
    __shared__ int fb_s;
    __shared__ u32 tot_s;
    __shared__ int b1_s;
    __shared__ int cnt_s;

    // ---- issue the 20 slab loads FIRST (uniform, before any branch): they fly
    //      while the cnts round + wave scan below execute (T14 issue-early) ----
    const u64* slab = prebuf + (size_t)b * NCH * LCAP;   // 5120 u64, contiguous
    u64 v[20];
#pragma unroll
    for (int k = 0; k < 20; ++k)                       // 20 coalesced loads in flight
        v[k] = slab[k * 256 + tid];

    // ---- single-wave scan of 320 counts: zero barriers inside ----
    if (tid < 64) {
        if (tid == 0) fb_s = 0;                        // wave-ordered before flag sets
        const u32* cb = cnts + b * NCH + tid * 5;
        u32 c0 = cb[0], c1 = cb[1], c2 = cb[2], c3 = cb[3], c4 = cb[4];
        if (c0 > LCAP || c1 > LCAP || c2 > LCAP || c3 > LCAP || c4 > LCAP) fb_s = 1;
        u32 l1 = c0 + c1, l2 = l1 + c2, l3 = l2 + c3, l4 = l3 + c4;
        u32 sum = l4;
#pragma unroll
        for (int off = 1; off < 64; off <<= 1) {       // wave-inclusive scan, no barriers
            u32 vv = __shfl_up(sum, off);
            if (tid >= off) sum += vv;
        }
        u32 base = sum - l4;                           // exclusive base for this lane
        int r = tid * 5;
        cc[r + 0] = c0; cc[r + 1] = c1; cc[r + 2] = c2; cc[r + 3] = c3; cc[r + 4] = c4;
        excl[r + 0] = base;
        excl[r + 1] = base + c0;
        excl[r + 2] = base + l1;
        excl[r + 3] = base + l2;
        excl[r + 4] = base + l3;
        if (tid == 63) {
            tot_s = sum;
            if (sum < KSEL || sum > CANDCAP) fb_s = 1;
        }
    }
    __syncthreads();                                   // barrier 1 (drains slab loads too)
    u32 tot = tot_s;
    int fb = fb_s;

    if (!fb) {
        // ---- scatter pre-loaded slab registers into compact LDS key array ----
#pragma unroll
        for (int k = 0; k < 20; ++k) {
            int s = k * 256 + tid;
            int r = s >> 4, l = s & 15;                // LCAP=16 regions
            if ((u32)l < cc[r]) keys[excl[r] + l] = v[k];
        }
        for (int i = tid; i < CANDCAP; i += 256)
            if ((u32)i >= tot) keys[i] = 0;            // pad: never outranks real keys
        __syncthreads();                               // barrier 2

        const int ci  = slice * 128 + (tid & 127);
        const int sub = tid >> 7;                      // wave-uniform (waves 0-1 vs 2-3)
        u64 mk = keys[ci];

        // prefetch decode operands (sub0 only); latency hides under rank loop.
        u32 combo = 0x3FFFFFu - (u32)(mk & 0xFFFFFFFFull);
        int cls = (int)(combo >> 18);
        int ridx = (int)(combo & 0x3FFFFu);
        float pr0 = 0, pr1 = 0, prs = 0, prc = 0, phg = 0;
        float pd0 = 0, pd1 = 0, pd2 = 0, pv0 = 0, pv1 = 0;
        if (sub == 0) {
            size_t base = (size_t)b * HW;
            pr0 = reg[((size_t)(b * 2 + 0)) * HW + ridx];
            pr1 = reg[((size_t)(b * 2 + 1)) * HW + ridx];
            prs = rot_sine[base + ridx];
            prc = rot_cosine[base + ridx];
            phg = hei[base + ridx];
            pd0 = dim[((size_t)(b * 3 + 0)) * HW + ridx];
            pd1 = dim[((size_t)(b * 3 + 1)) * HW + ridx];
            pd2 = dim[((size_t)(b * 3 + 2)) * HW + ridx];
            pv0 = vel[((size_t)(b * 2 + 0)) * HW + ridx];
            pv1 = vel[((size_t)(b * 2 + 1)) * HW + ridx];
        }

        // rank loop: b128 pair reads, tot-bounded, half-range per sub
        const ulonglong2* k2 = (const ulonglong2*)keys;
        u32 P  = (tot + 1) >> 1;                       // ~328 pairs
        u32 Pm = (P + 1) >> 1;
        u32 p0 = sub ? Pm : 0, p1 = sub ? P : Pm;
        u32 r = 0;
#pragma unroll 8
        for (u32 p = p0; p < p1; ++p) {                // broadcast ds_read_b128
            ulonglong2 kk = k2[p];
            r += (kk.x > mk) + (kk.y > mk);
        }
        partial[tid] = r;
        __syncthreads();                               // barrier 3
        if (tid < 128) {                               // sub0 threads hold prefetches
            int rank = (int)(partial[tid] + partial[tid + 128]);
            if (ci < (int)tot && rank < KSEL) {
                float score = u2f((u32)(mk >> 32));
                float xs = (float)(ridx & (WW - 1));
                float ys = (float)(ridx >> 9);
                float x = (xs + pr0) * 0.8f + (-51.2f);
                float y = (ys + pr1) * 0.8f + (-51.2f);
                float rot = atan2f(prs, prc);
                size_t obase = ((size_t)b * KSEL + rank) * 9;
                out[obase + 0] = x;
                out[obase + 1] = y;
                out[obase + 2] = phg;
                out[obase + 3] = pd0;
                out[obase + 4] = pd1;
                out[obase + 5] = pd2;
                out[obase + 6] = rot;
                out[obase + 7] = pv0;
                out[obase + 8] = pv1;
                const int NOUT = BB * KSEL;            // 4000
                out[9 * NOUT + b * KSEL + rank] = score;
                out[10 * NOUT + b * KSEL + rank] = (float)cls;
                bool keep = (x >= -61.2f) && (y >= -61.2f) && (phg >= -10.0f) &&
                            (x <= 61.2f) && (y <= 61.2f) && (phg <= 10.0f) &&
                            (score > 0.1f);
                out[11 * NOUT + b * KSEL + rank] = keep ? 1.0f : 0.0f;
            }
        }
        return;
    }

    // ---- exact fallback (not taken for this data; correctness safety net) ----
    if (slice != 0) return;
    for (int c = 0; c < CAT; ++c) {
        const float* hp = heat + (size_t)(b * CAT + c) * HW;
        for (int i = tid; i < NB; i += 256) h[i] = 0;
        if (tid == 0) cnt_s = 0;
        __syncthreads();
        for (int i = tid; i < HW; i += 256) atomicAdd(&h[bucketOf(hp[i])], 1u);
        __syncthreads();
        int b1 = find_b1_256(h, ps0, ps1, &b1_s);
        for (int i = tid; i < HW; i += 256) {
            float v2 = hp[i];
            if (bucketOf(v2) >= b1) {
                int pos = atomicAdd(&cnt_s, 1);
                if (pos < FBCAP)
                    cand[pos] = ((u64)f2u(v2) << 32) | (u32)(~(u32)i);
            }
        }
        __syncthreads();
        int c2 = min(cnt_s, FBCAP);
        for (int i = c2 + tid; i < FBCAP; i += 256) cand[i] = 0;
        __syncthreads();
        bitonic_sort_desc_256(cand);
        for (int r2 = tid; r2 < KSEL; r2 += 256) s1k[c * KSEL + r2] = cand[r2];
        __syncthreads();
    }
    // stage 2 over s1k[5000], tie-break by flat position
    const int NCAND = CAT * KSEL;
    for (int i = tid; i < NB; i += 256) h[i] = 0;
    if (tid == 0) cnt_s = 0;
    __syncthreads();
    for (int i = tid; i < NCAND; i += 256)
        atomicAdd(&h[bucketOf(u2f((u32)(s1k[i] >> 32)))], 1u);
    __syncthreads();
    int b1 = find_b1_256(h, ps0, ps1, &b1_s);
    for (int i = tid; i < NCAND; i += 256) {
        u64 k1 = s1k[i];
        float v2 = u2f((u32)(k1 >> 32));
        if (bucketOf(v2) >= b1) {
            int pos = atomicAdd(&cnt_s, 1);
            if (pos < FBCAP)
                cand[pos] = (k1 & 0xFFFFFFFF00000000ull) | (u32)(~(u32)i);
        }
    }
    __syncthreads();
    int c2 = min(cnt_s, FBCAP);
    for (int i = c2 + tid; i < FBCAP; i += 256) cand[i] = 0;
    __syncthreads();
    bitonic_sort_desc_256(cand);
    for (int r2 = tid; r2 < KSEL; r2 += 256) {
        u64 kk = cand[r2];
        float score = u2f((u32)(kk >> 32));
        int flat = (int)(~(u32)kk);
        int cls = flat / KSEL;
        int ridx = (int)(~(u32)s1k[flat]);
        decode_write(b, r2, score, cls, ridx,
                     rot_sine, rot_cosine, hei, dim, vel, reg, out);
    }
}

extern "C" void kernel_launch(void* const* d_in, const int* in_sizes, int n_in,
                              void* d_out, int out_size, void* d_ws, size_t ws_size,
                              hipStream_t stream) {
    const float* heat       = (const float*)d_in[0];
    const float* rot_sine   = (const float*)d_in[1];
    const float* rot_cosine = (const float*)d_in[2];
    const float* hei        = (const float*)d_in[3];
    const float* dim        = (const float*)d_in[4];
    const float* vel        = (const float*)d_in[5];
    const float* reg        = (const float*)d_in[6];

    char* ws = (char*)d_ws;
    // layout: cnts 80*32*4 = 10240 B | pad to 16384 | prebuf 80*32*16*8 = 327680 B
    u32* cnts   = (u32*)ws;
    u64* prebuf = (u64*)(ws + 16384);
    // no memset needed: every cnts slot is written unconditionally by k_prefilter

    k_prefilter<<<dim3(CHUNKS, BB * CAT), 256, 0, stream>>>(heat, cnts, prebuf);
    k_rank<<<dim3(SLICES, BB), 256, 0, stream>>>(heat, cnts, prebuf,
                                                 rot_sine, rot_cosine, hei, dim, vel, reg,
                                                 (float*)d_out);
}